// Round 3
// baseline (339.361 us; speedup 1.0000x reference)
//
#include <hip/hip_runtime.h>
#include <math.h>

typedef unsigned short us;
typedef __attribute__((ext_vector_type(8))) short frag8;
typedef __attribute__((ext_vector_type(4))) float f4;

#define B_   2
#define T_   1024
#define DM_  1024
#define D_   2048
#define N_   16
#define DTR_ 128
#define NDBC 160           // DTR + 2N
#define ROWS (B_*T_)       // 2048
#define EPS_ 1e-6f
#define NCH  32            // scan chunks per channel
#define CLEN (T_/NCH)      // 32 steps per chunk

__device__ __forceinline__ float us2f(us s){
    return __uint_as_float(((unsigned int)s) << 16);
}
__device__ __forceinline__ us f2us(float f){   // RTN-even fp32->bf16
    unsigned int u = __float_as_uint(f);
    return (us)((u + 0x7FFF + ((u >> 16) & 1)) >> 16);
}

// async global->LDS, 16B per lane. LDS dest is wave-uniform base + lane*16.
__device__ __forceinline__ void async16(const void* g, void* l){
    __builtin_amdgcn_global_load_lds(
        (const __attribute__((address_space(1))) void*)g,
        (__attribute__((address_space(3)))       void*)l, 16, 0, 0);
}

// one DPP row_ror:K accumulate step (dpp_ctrl must be a literal constant)
template<int CTRL>
__device__ __forceinline__ float dpp_add(float x){
    int t = __builtin_amdgcn_update_dpp(0, __float_as_int(x), CTRL, 0xF, 0xF, true);
    return x + __int_as_float(t);
}
// 16-lane sum via DPP row_ror (VALU pipe, no DS ops)
__device__ __forceinline__ float sum16_dpp(float x){
    x = dpp_add<0x128>(x);   // row_ror:8
    x = dpp_add<0x124>(x);   // row_ror:4
    x = dpp_add<0x122>(x);   // row_ror:2
    x = dpp_add<0x121>(x);   // row_ror:1
    return x;
}

// ---- combined weight prep: 4 matrices fp32 [R][C] -> bf16 [C][R] ----
__global__ __launch_bounds__(256) void prep_weights(
    const float* __restrict__ in_W,  const float* __restrict__ out_W,
    const float* __restrict__ dbc_W, const float* __restrict__ dup_W,
    us* __restrict__ inWt, us* __restrict__ outWt,
    us* __restrict__ dbcWt, us* __restrict__ dupWt)
{
    __shared__ us tile[32][33];
    int bid = blockIdx.x;
    const float* src; us* dst; int C, R, TX, rel;
    if (bid < 4096)      { src = in_W;  dst = inWt;  R = 1024; C = 4096; TX = 128; rel = bid; }
    else if (bid < 6144) { src = out_W; dst = outWt; R = 2048; C = 1024; TX = 32;  rel = bid - 4096; }
    else if (bid < 6464) { src = dbc_W; dst = dbcWt; R = 2048; C = 160;  TX = 5;   rel = bid - 6144; }
    else                 { src = dup_W; dst = dupWt; R = 128;  C = 2048; TX = 64;  rel = bid - 6464; }
    int c0 = (rel % TX) * 32, r0 = (rel / TX) * 32;
    int tx = threadIdx.x, ty = threadIdx.y;   // 32 x 8
    for (int i = ty; i < 32; i += 8)
        tile[i][tx] = f2us(src[(size_t)(r0 + i) * C + c0 + tx]);
    __syncthreads();
    for (int i = ty; i < 32; i += 8)
        dst[(size_t)(c0 + i) * R + r0 + tx] = tile[tx][i];
}

// ------------- bf16 [R][C] -> bf16 [C][R] (dims multiples of 32) -------------
__global__ __launch_bounds__(256) void transpose_us(const us* __restrict__ in,
                                                    us* __restrict__ out, int R, int C)
{
    __shared__ us tile[32][33];
    int c0 = blockIdx.x * 32, r0 = blockIdx.y * 32;
    int tx = threadIdx.x, ty = threadIdx.y;   // 32 x 8
    for (int i = ty; i < 32; i += 8)
        tile[i][tx] = in[(size_t)(r0 + i) * C + c0 + tx];
    __syncthreads();
    for (int i = ty; i < 32; i += 8)
        out[(size_t)(c0 + i) * R + r0 + tx] = tile[tx][i];
}

// ---------------- fused RMSNorm -> bf16 h, one block per row ----------------
__global__ __launch_bounds__(256) void rmshbf_kernel(const float* __restrict__ x,
                                                     const float* __restrict__ rms_w,
                                                     us* __restrict__ hbf)
{
    const int row = blockIdx.x;
    const float* xr = x + (size_t)row * DM_;
    const int tid = threadIdx.x;
    float vals[4], ss = 0.f;
#pragma unroll
    for (int i = 0; i < 4; ++i) { vals[i] = xr[tid + i*256]; ss += vals[i]*vals[i]; }
#pragma unroll
    for (int off = 32; off >= 1; off >>= 1) ss += __shfl_xor(ss, off, 64);
    __shared__ float red[4];
    if ((tid & 63) == 0) red[tid >> 6] = ss;
    __syncthreads();
    float scale = rsqrtf((red[0]+red[1]+red[2]+red[3]) / (float)DM_ + EPS_);
#pragma unroll
    for (int i = 0; i < 4; ++i)
        hbf[(size_t)row * DM_ + tid + i*256] = f2us(vals[i] * scale * rms_w[tid + i*256]);
}

// ---------- MFMA GEMM: C[M,N] = A[M,K](bf16) * Bt[N,K](bf16)^T + bias --------
// 128x128 tile / 4 waves; wave 64x64 via 4x4 mfma_f32_16x16x32_bf16.
// Staging via global_load_lds width=16: unpadded [128][64] LDS, 2-barrier
// K-loop. OOB B rows read adjacent mapped ws; poisoned acc lands only in
// col>=N tiles which the epilogue discards.
// RB: bias indexed by M-row. EPI 0: fp32. 1: cheap softplus fp32. 2: +resid.
// EPI 3: bf16 aux col<DTR + fp32 B/C transposed into bct[32][ROWS] (no Cf).
// EPI 4: col<D fp32 Cf; col>=D bf16 Caux.
template<int EPI, bool RB>
__global__ __launch_bounds__(256) void mgemm(
    const us*    __restrict__ A,     // [M][K]
    const us*    __restrict__ Bt,    // [N][K]
    const float* __restrict__ bias,
    float*       __restrict__ Cf,
    us*          __restrict__ Caux,
    const float* __restrict__ resid, // EPI==2
    float*       __restrict__ bct,   // EPI==3
    int M, int N, int K)
{
    __shared__ us As[128*64];
    __shared__ us Bs[128*64];
    const int tid = threadIdx.x;
    const int bm = blockIdx.y * 128;
    const int bn = blockIdx.x * 128;
    const int w = tid >> 6, lane = tid & 63;
    const int wr = w >> 1, wc = w & 1;
    const int m16 = lane & 15, quad = lane >> 4;

    f4 acc[4][4];
#pragma unroll
    for (int i = 0; i < 4; ++i)
#pragma unroll
        for (int j = 0; j < 4; ++j)
            acc[i][j] = (f4){0.f, 0.f, 0.f, 0.f};

    for (int k0 = 0; k0 < K; k0 += 64) {
        __syncthreads();   // prior iter's frag reads done before overwrite
#pragma unroll
        for (int q = 0; q < 4; ++q) {
            int cb = (w*4 + q)*64 + lane;       // 16B-chunk id 0..1023
            int row = cb >> 3, c8 = (cb & 7)*8;
            async16(A  + (size_t)(bm + row) * K + k0 + c8, &As[cb*8]);
            async16(Bt + (size_t)(bn + row) * K + k0 + c8, &Bs[cb*8]);
        }
        __syncthreads();   // vmcnt(0) drained here -> LDS valid
#pragma unroll
        for (int ks = 0; ks < 64; ks += 32) {
            frag8 af[4], bfr[4];
#pragma unroll
            for (int i = 0; i < 4; ++i)
                af[i] = *(const frag8*)&As[(wr*64 + i*16 + m16)*64 + ks + quad*8];
#pragma unroll
            for (int j = 0; j < 4; ++j)
                bfr[j] = *(const frag8*)&Bs[(wc*64 + j*16 + m16)*64 + ks + quad*8];
#pragma unroll
            for (int i = 0; i < 4; ++i)
#pragma unroll
                for (int j = 0; j < 4; ++j)
                    acc[i][j] = __builtin_amdgcn_mfma_f32_16x16x32_bf16(af[i], bfr[j], acc[i][j], 0, 0, 0);
        }
    }

#pragma unroll
    for (int i = 0; i < 4; ++i) {
#pragma unroll
        for (int j = 0; j < 4; ++j) {
            int col = bn + wc*64 + j*16 + m16;
            if (col >= N) continue;
            float bvc = RB ? 0.f : bias[col];
#pragma unroll
            for (int r = 0; r < 4; ++r) {
                int row = bm + wr*64 + i*16 + quad*4 + r;
                float v = acc[i][j][r] + (RB ? bias[row] : bvc);
                if constexpr (EPI == 1) {
                    v = fmaxf(v, 0.f) + __logf(1.f + __expf(-fabsf(v)));
                    Cf[(size_t)row * N + col] = v;
                } else if constexpr (EPI == 2) {
                    v += resid[(size_t)row * N + col];
                    Cf[(size_t)row * N + col] = v;
                } else if constexpr (EPI == 3) {
                    if (col < DTR_) Caux[(size_t)row * DTR_ + col] = f2us(v);
                    else            bct [(size_t)(col - DTR_) * ROWS + row] = v;
                } else if constexpr (EPI == 4) {
                    if (col < D_) Cf  [(size_t)row * D_ + col]        = v;
                    else          Caux[(size_t)row * D_ + (col - D_)] = f2us(v);
                } else {
                    Cf[(size_t)row * N + col] = v;
                }
            }
        }
    }
}

// --- depthwise causal conv (K=4) + SiLU, dual-layout x1 out + g transpose ---
__global__ __launch_bounds__(256) void conv_silu_kernel(
    const float* __restrict__ x1pre,
    const us*    __restrict__ g_rm,
    const float* __restrict__ cw,
    const float* __restrict__ cb,
    us*          __restrict__ x1cb,
    us*          __restrict__ x1tb,
    us*          __restrict__ g_t)
{
    __shared__ us tileX[32][33];
    __shared__ us tileG[32][33];
    const int tx = threadIdx.x, ty = threadIdx.y;   // 32 x 8
    const int d0 = blockIdx.x * 32, r0 = blockIdx.y * 32;
    const int d = d0 + tx;
    const float w0 = cw[d*4+0], w1 = cw[d*4+1], w2 = cw[d*4+2], w3 = cw[d*4+3];
    const float bias = cb[d];
    for (int i = ty; i < 32; i += 8) {
        int row = r0 + i;
        int t = row & (T_ - 1);
        const float* base = x1pre + (size_t)row * D_ + d;
        float acc = bias;
        acc = fmaf(w3, base[0], acc);
        if (t >= 1) acc = fmaf(w2, base[-D_],   acc);
        if (t >= 2) acc = fmaf(w1, base[-2*D_], acc);
        if (t >= 3) acc = fmaf(w0, base[-3*D_], acc);
        float sg = 1.f / (1.f + __expf(-acc));
        us uv = f2us(acc * sg);
        x1cb[(size_t)row * D_ + d] = uv;
        tileX[i][tx] = uv;
        tileG[i][tx] = g_rm[(size_t)row * D_ + d];
    }
    __syncthreads();
    for (int i = ty; i < 32; i += 8) {
        x1tb[(size_t)(d0 + i) * ROWS + r0 + tx] = tileX[tx][i];
        g_t [(size_t)(d0 + i) * ROWS + r0 + tx] = tileG[tx][i];
    }
}

// ------- chunked selective scan + gate, one block per (b,d) channel ----------
// v4: (a) __launch_bounds__(512,4) lifts the implicit 8-waves/SIMD 64-VGPR cap
// that forced v2/v3's spill/remat (VGPR_Count=56 both rounds); (b) B/C read
// from bct[32][ROWS] (written transposed by the dbc-GEMM epilogue) as 8 named
// float4 loads per operand -- deletes 64 strided scalar loads + their address
// chains; (c) pass-1 intermediates carried to pass 2 in named scalars.
// Pass 2 per step: fma + mul + 4 dpp + masked LDS write. No exp, no loads.
#define RPT32(M) M(0) M(1) M(2) M(3) M(4) M(5) M(6) M(7) \
                 M(8) M(9) M(10) M(11) M(12) M(13) M(14) M(15) \
                 M(16) M(17) M(18) M(19) M(20) M(21) M(22) M(23) \
                 M(24) M(25) M(26) M(27) M(28) M(29) M(30) M(31)
#define RPT8(M) M(0) M(1) M(2) M(3) M(4) M(5) M(6) M(7)

__global__ __launch_bounds__(512, 4) void scan_block_kernel(
    const float* __restrict__ delta_t,
    const us*    __restrict__ x1tb,
    const float* __restrict__ bct,    // [32][ROWS]: rows 0..15 = B_n, 16..31 = C_n
    const float* __restrict__ A_log,
    const us*    __restrict__ g_t,
    us*          __restrict__ y_t)
{
    __shared__ float2 ddx[T_ + NCH];  // (delta, delta*x), swizzle f(t)=t+(t>>6)
    __shared__ float  ys [T_ + NCH];
    __shared__ float  Pl[NCH][N_];
    __shared__ float  Sl[NCH][N_];

    const int tid = threadIdx.x;
    const int d = blockIdx.x & (D_ - 1);
    const int b = blockIdx.x >> 11;
    const int n = tid & 15;
    const int c = tid >> 4;            // chunk 0..31
    const size_t rb = (size_t)b * T_;
    const size_t cb0 = (size_t)d * ROWS + rb;

    {   // coalesced staging: 2 elems/thread
        int i = tid * 2;
        int fi = i + (i >> 6);        // i even -> fi,fi+1 = f(i),f(i+1)
        float2 dv2 = *(const float2*)&delta_t[cb0 + i];
        ushort2 ux = *(const ushort2*)&x1tb  [cb0 + i];
        ddx[fi+0] = (float2){dv2.x, dv2.x * us2f(ux.x)};
        ddx[fi+1] = (float2){dv2.y, dv2.y * us2f(ux.y)};
    }
    const float a_coef = -__expf(A_log[d * N_ + n]);

    const int t0 = c * CLEN;
    // t0 is a multiple of 32 and j<32 never crosses a 64-boundary, so
    // (t0+j)>>6 == t0>>6 for all j: the swizzle base is loop-invariant.
    const int ft0 = t0 + (t0 >> 6);
    const float* __restrict__ bbase = bct + (size_t)n * ROWS + rb + t0;
    const float* __restrict__ cbase = bbase + (size_t)N_ * ROWS;

    // B chunk: 8 independent float4 loads, issued before the barrier so the
    // latency overlaps the staging drain. Named vars (no arrays -> no scratch).
#define DECLB(Q) f4 B##Q = *(const f4*)&bbase[(Q)*4];
    RPT8(DECLB)
#undef DECLB

    __syncthreads();

#define DECLAD(J) float a##J, d##J;
    RPT32(DECLAD)
#undef DECLAD

    float P = 1.f, S = 0.f;
#define P1(J, BV) { \
        float2 dd = ddx[ft0 + (J)]; \
        a##J = __expf(dd.x * a_coef); \
        d##J = dd.y * (BV); \
        P *= a##J; \
        S = fmaf(a##J, S, d##J); }
    P1(0,B0[0]) P1(1,B0[1]) P1(2,B0[2]) P1(3,B0[3])
    P1(4,B1[0]) P1(5,B1[1]) P1(6,B1[2]) P1(7,B1[3])
    P1(8,B2[0]) P1(9,B2[1]) P1(10,B2[2]) P1(11,B2[3])
    P1(12,B3[0]) P1(13,B3[1]) P1(14,B3[2]) P1(15,B3[3])
    P1(16,B4[0]) P1(17,B4[1]) P1(18,B4[2]) P1(19,B4[3])
    P1(20,B5[0]) P1(21,B5[1]) P1(22,B5[2]) P1(23,B5[3])
    P1(24,B6[0]) P1(25,B6[1]) P1(26,B6[2]) P1(27,B6[3])
    P1(28,B7[0]) P1(29,B7[1]) P1(30,B7[2]) P1(31,B7[3])
#undef P1

    Pl[c][n] = P;
    Sl[c][n] = S;
    __syncthreads();

    float h = 0.f;
    for (int c2 = 0; c2 < c; ++c2)
        h = fmaf(Pl[c2][n], h, Sl[c2][n]);

    // C chunk: 8 independent float4 loads (L2/L3-hot, 256 KB total)
#define DECLC(Q) f4 C##Q = *(const f4*)&cbase[(Q)*4];
    RPT8(DECLC)
#undef DECLC

#define P2(J, CV) { \
        h = fmaf(a##J, h, d##J); \
        float pr = sum16_dpp(h * (CV)); \
        if (n == 0) ys[ft0 + (J)] = pr; }
    P2(0,C0[0]) P2(1,C0[1]) P2(2,C0[2]) P2(3,C0[3])
    P2(4,C1[0]) P2(5,C1[1]) P2(6,C1[2]) P2(7,C1[3])
    P2(8,C2[0]) P2(9,C2[1]) P2(10,C2[2]) P2(11,C2[3])
    P2(12,C3[0]) P2(13,C3[1]) P2(14,C3[2]) P2(15,C3[3])
    P2(16,C4[0]) P2(17,C4[1]) P2(18,C4[2]) P2(19,C4[3])
    P2(20,C5[0]) P2(21,C5[1]) P2(22,C5[2]) P2(23,C5[3])
    P2(24,C6[0]) P2(25,C6[1]) P2(26,C6[2]) P2(27,C6[3])
    P2(28,C7[0]) P2(29,C7[1]) P2(30,C7[2]) P2(31,C7[3])
#undef P2

    __syncthreads();
    {   // coalesced output: apply gate full-width, store bf16
        int i = tid * 2;
        int fi = i + (i >> 6);
        ushort2 ug = *(const ushort2*)&g_t[cb0 + i];
        float g0 = us2f(ug.x), g1 = us2f(ug.y);
        float y0 = ys[fi+0] * g0 * (1.f / (1.f + __expf(-g0)));
        float y1 = ys[fi+1] * g1 * (1.f / (1.f + __expf(-g1)));
        ushort2 uy;
        uy.x = f2us(y0); uy.y = f2us(y1);
        *(ushort2*)&y_t[cb0 + i] = uy;
    }
}

extern "C" void kernel_launch(void* const* d_in, const int* in_sizes, int n_in,
                              void* d_out, int out_size, void* d_ws, size_t ws_size,
                              hipStream_t stream)
{
    const float* x      = (const float*)d_in[0];
    const float* rms_w  = (const float*)d_in[1];
    const float* in_W   = (const float*)d_in[2];
    const float* in_b   = (const float*)d_in[3];
    const float* conv_w = (const float*)d_in[4];
    const float* conv_b = (const float*)d_in[5];
    const float* A_log  = (const float*)d_in[6];
    const float* dbc_W  = (const float*)d_in[7];
    const float* dbc_b  = (const float*)d_in[8];
    const float* dup_W  = (const float*)d_in[9];
    const float* dup_b  = (const float*)d_in[10];
    const float* out_W  = (const float*)d_in[11];
    const float* out_b  = (const float*)d_in[12];
    float* out = (float*)d_out;

    // ---- workspace layout (~83 MB; 89.3 MB proven available) ----
    float* ws      = (float*)d_ws;
    float* x1pre   = ws;                           // 16 MB fp32 [rows][D], dead after conv
    us* g_rm  = (us*)(x1pre + (size_t)ROWS*D_);    // 8 MB bf16 [rows][D], dead after conv
    us* g_t   = g_rm  + (size_t)ROWS*D_;           // 8 MB bf16 [d][rows]
    float* bct     = (float*)(g_t + (size_t)ROWS*D_); // 256 KB fp32 [32][rows] (B then C)
    float* delta_t = bct + (size_t)2*N_*ROWS;      // 16 MB fp32 [d][rows]
    us* hbf   = (us*)(delta_t + (size_t)ROWS*D_);  // 4 MB
    us* x1cb  = hbf   + (size_t)ROWS*DM_;          // 8 MB [rows][D], dead after dbc-GEMM
    us* x1tb  = x1cb  + (size_t)ROWS*D_;           // 8 MB [d][rows]
    us* dtrb  = x1tb  + (size_t)ROWS*D_;           // 0.5 MB [rows][DTR]
    us* inWt  = dtrb  + (size_t)ROWS*DTR_;         // 8 MB  [4096][1024]
    us* dbcWt = inWt  + (size_t)2*D_*DM_;          // 0.64 MB [160][2048]
    us* dupWt = dbcWt + (size_t)NDBC*D_;           // 0.5 MB [2048][128]
    us* outWt = dupWt + (size_t)D_*DTR_;           // 4 MB  [1024][2048]
    us* y_t   = (us*)x1pre;                        // alias (x1pre dead), [d][rows]
    us* ybf   = x1cb;                              // alias (x1cb dead), [rows][D]

    dim3 tb(32, 8);
    // 1. weight prep
    prep_weights<<<6720, tb, 0, stream>>>(in_W, out_W, dbc_W, dup_W,
                                          inWt, outWt, dbcWt, dupWt);
    // 2. fused rmsnorm -> hbf (bf16)
    rmshbf_kernel<<<ROWS, 256, 0, stream>>>(x, rms_w, hbf);
    // 3. fused in_proj: x1pre fp32 + g_rm bf16 (both row-major)  [2048 x 4096], K=1024
    mgemm<4,false><<<dim3(32, 16), 256, 0, stream>>>(
        hbf, inWt, in_b, x1pre, g_rm, nullptr, nullptr, ROWS, 2*D_, DM_);
    // 4. conv + silu -> x1cb + x1tb ; g_rm -> g_t transpose
    conv_silu_kernel<<<dim3(D_/32, ROWS/32), tb, 0, stream>>>(
        x1pre, g_rm, conv_w, conv_b, x1cb, x1tb, g_t);
    // 5. dbc = x1c @ dbc_W + dbc_b  [2048 x 160], K=2048
    //    -> bf16 aux (cols<128) + transposed fp32 B/C into bct[32][rows]
    mgemm<3,false><<<dim3(2, 16), 256, 0, stream>>>(
        x1cb, dbcWt, dbc_b, nullptr, dtrb, nullptr, bct, ROWS, NDBC, D_);
    // 6. delta_t = softplus(dup_W^T @ dtr^T + dup_b)  [2048 x 2048], K=128
    mgemm<1,true><<<dim3(16, 16), 256, 0, stream>>>(
        dupWt, dtrb, dup_b, delta_t, nullptr, nullptr, nullptr, D_, ROWS, DTR_);
    // 7. chunked selective scan + gate -> y_t [d][rows]
    scan_block_kernel<<<B_*D_, 512, 0, stream>>>(delta_t, x1tb, bct, A_log, g_t, y_t);
    // 8. y_t -> ybf [rows][D]
    transpose_us<<<dim3(ROWS/32, D_/32), tb, 0, stream>>>(y_t, ybf, D_, ROWS);
    // 9. out = y @ out_W + out_b + residual   [2048 x 1024], K=2048
    mgemm<2,false><<<dim3(8, 16), 256, 0, stream>>>(
        ybf, outWt, out_b, out, nullptr, x, nullptr, ROWS, DM_, D_);
}

// Round 4
// 308.507 us; speedup vs baseline: 1.1000x; 1.1000x over previous
//
#include <hip/hip_runtime.h>
#include <math.h>

typedef unsigned short us;
typedef __attribute__((ext_vector_type(8))) short frag8;
typedef __attribute__((ext_vector_type(8))) unsigned short u8v;
typedef __attribute__((ext_vector_type(4))) float f4;
typedef __attribute__((ext_vector_type(2))) float f2;

#define B_   2
#define T_   1024
#define DM_  1024
#define D_   2048
#define N_   16
#define DTR_ 128
#define NDBC 160           // DTR + 2N
#define ROWS (B_*T_)       // 2048
#define EPS_ 1e-6f
#define NCH  32            // scan chunks per channel
#define CLEN (T_/NCH)      // 32 steps per chunk

__device__ __forceinline__ float us2f(us s){
    return __uint_as_float(((unsigned int)s) << 16);
}
__device__ __forceinline__ us f2us(float f){   // RTN-even fp32->bf16
    unsigned int u = __float_as_uint(f);
    return (us)((u + 0x7FFF + ((u >> 16) & 1)) >> 16);
}

// async global->LDS, 16B per lane. LDS dest is wave-uniform base + lane*16.
__device__ __forceinline__ void async16(const void* g, void* l){
    __builtin_amdgcn_global_load_lds(
        (const __attribute__((address_space(1))) void*)g,
        (__attribute__((address_space(3)))       void*)l, 16, 0, 0);
}

// one DPP accumulate step (dpp_ctrl must be a literal constant)
template<int CTRL>
__device__ __forceinline__ float dpp_add(float x){
    int t = __builtin_amdgcn_update_dpp(0, __float_as_int(x), CTRL, 0xF, 0xF, true);
    return x + __int_as_float(t);
}
// 4-lane (quad) sum via two quad_perm DPP adds; all 4 lanes get the total
__device__ __forceinline__ float sum4_quad(float x){
    x = dpp_add<0xB1>(x);   // quad_perm [1,0,3,2]
    x = dpp_add<0x4E>(x);   // quad_perm [2,3,0,1]
    return x;
}

// ---- combined weight prep: 4 matrices fp32 [R][C] -> bf16 [C][R] ----
__global__ __launch_bounds__(256) void prep_weights(
    const float* __restrict__ in_W,  const float* __restrict__ out_W,
    const float* __restrict__ dbc_W, const float* __restrict__ dup_W,
    us* __restrict__ inWt, us* __restrict__ outWt,
    us* __restrict__ dbcWt, us* __restrict__ dupWt)
{
    __shared__ us tile[32][33];
    int bid = blockIdx.x;
    const float* src; us* dst; int C, R, TX, rel;
    if (bid < 4096)      { src = in_W;  dst = inWt;  R = 1024; C = 4096; TX = 128; rel = bid; }
    else if (bid < 6144) { src = out_W; dst = outWt; R = 2048; C = 1024; TX = 32;  rel = bid - 4096; }
    else if (bid < 6464) { src = dbc_W; dst = dbcWt; R = 2048; C = 160;  TX = 5;   rel = bid - 6144; }
    else                 { src = dup_W; dst = dupWt; R = 128;  C = 2048; TX = 64;  rel = bid - 6464; }
    int c0 = (rel % TX) * 32, r0 = (rel / TX) * 32;
    int tx = threadIdx.x, ty = threadIdx.y;   // 32 x 8
    for (int i = ty; i < 32; i += 8)
        tile[i][tx] = f2us(src[(size_t)(r0 + i) * C + c0 + tx]);
    __syncthreads();
    for (int i = ty; i < 32; i += 8)
        dst[(size_t)(c0 + i) * R + r0 + tx] = tile[tx][i];
}

// ------------- bf16 [R][C] -> bf16 [C][R] (dims multiples of 32) -------------
__global__ __launch_bounds__(256) void transpose_us(const us* __restrict__ in,
                                                    us* __restrict__ out, int R, int C)
{
    __shared__ us tile[32][33];
    int c0 = blockIdx.x * 32, r0 = blockIdx.y * 32;
    int tx = threadIdx.x, ty = threadIdx.y;   // 32 x 8
    for (int i = ty; i < 32; i += 8)
        tile[i][tx] = in[(size_t)(r0 + i) * C + c0 + tx];
    __syncthreads();
    for (int i = ty; i < 32; i += 8)
        out[(size_t)(c0 + i) * R + r0 + tx] = tile[tx][i];
}

// ---------------- fused RMSNorm -> bf16 h, one block per row ----------------
__global__ __launch_bounds__(256) void rmshbf_kernel(const float* __restrict__ x,
                                                     const float* __restrict__ rms_w,
                                                     us* __restrict__ hbf)
{
    const int row = blockIdx.x;
    const float* xr = x + (size_t)row * DM_;
    const int tid = threadIdx.x;
    float vals[4], ss = 0.f;
#pragma unroll
    for (int i = 0; i < 4; ++i) { vals[i] = xr[tid + i*256]; ss += vals[i]*vals[i]; }
#pragma unroll
    for (int off = 32; off >= 1; off >>= 1) ss += __shfl_xor(ss, off, 64);
    __shared__ float red[4];
    if ((tid & 63) == 0) red[tid >> 6] = ss;
    __syncthreads();
    float scale = rsqrtf((red[0]+red[1]+red[2]+red[3]) / (float)DM_ + EPS_);
#pragma unroll
    for (int i = 0; i < 4; ++i)
        hbf[(size_t)row * DM_ + tid + i*256] = f2us(vals[i] * scale * rms_w[tid + i*256]);
}

// ---------- MFMA GEMM: C[M,N] = A[M,K](bf16) * Bt[N,K](bf16)^T + bias --------
// 128x128 tile / 4 waves; wave 64x64 via 4x4 mfma_f32_16x16x32_bf16.
// Staging via global_load_lds width=16: unpadded [128][64] LDS, 2-barrier
// K-loop. OOB B rows read adjacent mapped ws; poisoned acc lands only in
// col>=N tiles which the epilogue discards.
// RB: bias indexed by M-row. EPI 0: fp32. 1: cheap softplus fp32. 2: +resid.
// EPI 3: bf16 aux col<DTR + fp32 B/C into bct[ROWS][32] (no Cf).
// EPI 4: col<D fp32 Cf; col>=D bf16 Caux.
template<int EPI, bool RB>
__global__ __launch_bounds__(256) void mgemm(
    const us*    __restrict__ A,     // [M][K]
    const us*    __restrict__ Bt,    // [N][K]
    const float* __restrict__ bias,
    float*       __restrict__ Cf,
    us*          __restrict__ Caux,
    const float* __restrict__ resid, // EPI==2
    float*       __restrict__ bct,   // EPI==3
    int M, int N, int K)
{
    __shared__ us As[128*64];
    __shared__ us Bs[128*64];
    const int tid = threadIdx.x;
    const int bm = blockIdx.y * 128;
    const int bn = blockIdx.x * 128;
    const int w = tid >> 6, lane = tid & 63;
    const int wr = w >> 1, wc = w & 1;
    const int m16 = lane & 15, quad = lane >> 4;

    f4 acc[4][4];
#pragma unroll
    for (int i = 0; i < 4; ++i)
#pragma unroll
        for (int j = 0; j < 4; ++j)
            acc[i][j] = (f4){0.f, 0.f, 0.f, 0.f};

    for (int k0 = 0; k0 < K; k0 += 64) {
        __syncthreads();   // prior iter's frag reads done before overwrite
#pragma unroll
        for (int q = 0; q < 4; ++q) {
            int cb = (w*4 + q)*64 + lane;       // 16B-chunk id 0..1023
            int row = cb >> 3, c8 = (cb & 7)*8;
            async16(A  + (size_t)(bm + row) * K + k0 + c8, &As[cb*8]);
            async16(Bt + (size_t)(bn + row) * K + k0 + c8, &Bs[cb*8]);
        }
        __syncthreads();   // vmcnt(0) drained here -> LDS valid
#pragma unroll
        for (int ks = 0; ks < 64; ks += 32) {
            frag8 af[4], bfr[4];
#pragma unroll
            for (int i = 0; i < 4; ++i)
                af[i] = *(const frag8*)&As[(wr*64 + i*16 + m16)*64 + ks + quad*8];
#pragma unroll
            for (int j = 0; j < 4; ++j)
                bfr[j] = *(const frag8*)&Bs[(wc*64 + j*16 + m16)*64 + ks + quad*8];
#pragma unroll
            for (int i = 0; i < 4; ++i)
#pragma unroll
                for (int j = 0; j < 4; ++j)
                    acc[i][j] = __builtin_amdgcn_mfma_f32_16x16x32_bf16(af[i], bfr[j], acc[i][j], 0, 0, 0);
        }
    }

#pragma unroll
    for (int i = 0; i < 4; ++i) {
#pragma unroll
        for (int j = 0; j < 4; ++j) {
            int col = bn + wc*64 + j*16 + m16;
            if (col >= N) continue;
            float bvc = RB ? 0.f : bias[col];
#pragma unroll
            for (int r = 0; r < 4; ++r) {
                int row = bm + wr*64 + i*16 + quad*4 + r;
                float v = acc[i][j][r] + (RB ? bias[row] : bvc);
                if constexpr (EPI == 1) {
                    v = fmaxf(v, 0.f) + __logf(1.f + __expf(-fabsf(v)));
                    Cf[(size_t)row * N + col] = v;
                } else if constexpr (EPI == 2) {
                    v += resid[(size_t)row * N + col];
                    Cf[(size_t)row * N + col] = v;
                } else if constexpr (EPI == 3) {
                    if (col < DTR_) Caux[(size_t)row * DTR_ + col] = f2us(v);
                    else            bct [(size_t)row * 32 + (col - DTR_)] = v;
                } else if constexpr (EPI == 4) {
                    if (col < D_) Cf  [(size_t)row * D_ + col]        = v;
                    else          Caux[(size_t)row * D_ + (col - D_)] = f2us(v);
                } else {
                    Cf[(size_t)row * N + col] = v;
                }
            }
        }
    }
}

// --- depthwise causal conv (K=4) + SiLU, dual-layout x1 out + g transpose ---
__global__ __launch_bounds__(256) void conv_silu_kernel(
    const float* __restrict__ x1pre,
    const us*    __restrict__ g_rm,
    const float* __restrict__ cw,
    const float* __restrict__ cb,
    us*          __restrict__ x1cb,
    us*          __restrict__ x1tb,
    us*          __restrict__ g_t)
{
    __shared__ us tileX[32][33];
    __shared__ us tileG[32][33];
    const int tx = threadIdx.x, ty = threadIdx.y;   // 32 x 8
    const int d0 = blockIdx.x * 32, r0 = blockIdx.y * 32;
    const int d = d0 + tx;
    const float w0 = cw[d*4+0], w1 = cw[d*4+1], w2 = cw[d*4+2], w3 = cw[d*4+3];
    const float bias = cb[d];
    for (int i = ty; i < 32; i += 8) {
        int row = r0 + i;
        int t = row & (T_ - 1);
        const float* base = x1pre + (size_t)row * D_ + d;
        float acc = bias;
        acc = fmaf(w3, base[0], acc);
        if (t >= 1) acc = fmaf(w2, base[-D_],   acc);
        if (t >= 2) acc = fmaf(w1, base[-2*D_], acc);
        if (t >= 3) acc = fmaf(w0, base[-3*D_], acc);
        float sg = 1.f / (1.f + __expf(-acc));
        us uv = f2us(acc * sg);
        x1cb[(size_t)row * D_ + d] = uv;
        tileX[i][tx] = uv;
        tileG[i][tx] = g_rm[(size_t)row * D_ + d];
    }
    __syncthreads();
    for (int i = ty; i < 32; i += 8) {
        x1tb[(size_t)(d0 + i) * ROWS + r0 + tx] = tileX[tx][i];
        g_t [(size_t)(d0 + i) * ROWS + r0 + tx] = tileG[tx][i];
    }
}

// ------- chunked selective scan + gate, one block per (b,d) channel ----------
// v5: NEW DECOMPOSITION. 128 threads = (chunk c 0..31) x (state-group ng 0..3);
// each thread owns 4 states of one 32-step chunk. delta/x read DIRECTLY from
// global (thread-contiguous, f4/16B) -- no ddx LDS staging at all. B/C read as
// one float4 per step from bct[row][32]. State math in f2 vectors (v_pk_*
// eligible). 16-state reduce = 3 adds + 2 quad_perm DPP (states sit in one
// 4-lane quad). Pass 2 recomputes a/d (cheap, L2-hot reloads) instead of
// carrying 64 regs -- keeps VGPR small, occupancy high (the v2-v4 lesson:
// carrying trades occupancy 8->4 waves/SIMD and nets zero).
__global__ __launch_bounds__(128, 6) void scan_block_kernel(
    const float* __restrict__ delta_t,
    const us*    __restrict__ x1tb,
    const float* __restrict__ bct,    // [rows][32]: [0:16]=B_n, [16:32]=C_n
    const float* __restrict__ A_log,
    const us*    __restrict__ g_t,
    us*          __restrict__ y_t)
{
    __shared__ float ys[T_ + NCH];    // swizzle f(t) = t + (t>>5)
    __shared__ f4 PSl[NCH][9];        // [c][2ng+(0,1)] = {P.x,P.y,S.x,S.y}; +1 pad

    const int tid = threadIdx.x;       // 128
    const int d  = blockIdx.x & (D_ - 1);
    const int b  = blockIdx.x >> 11;
    const int ng = tid & 3;            // states 4ng .. 4ng+3
    const int c  = tid >> 2;           // chunk 0..31
    const size_t rb  = (size_t)b * T_;
    const size_t cb0 = (size_t)d * ROWS + rb;
    const int t0 = c * CLEN;

    // 4 per-state coefficients a_coef_n = -exp(A_log[d][n])
    f4 al = *(const f4*)&A_log[d * N_ + ng * 4];
    const f2 ac01 = (f2){-__expf(al[0]), -__expf(al[1])};
    const f2 ac23 = (f2){-__expf(al[2]), -__expf(al[3])};

    const float* __restrict__ dp = delta_t + cb0 + t0;
    const us*    __restrict__ xp = x1tb   + cb0 + t0;
    const float* __restrict__ bp = bct + (size_t)(rb + t0) * 32 + ng * 4;
    const float* __restrict__ cp = bp + 16;

    // ---------------- pass 1: per-chunk (P, S) ----------------
    f2 P01 = (f2){1.f, 1.f}, P23 = (f2){1.f, 1.f};
    f2 S01 = (f2){0.f, 0.f}, S23 = (f2){0.f, 0.f};
#pragma unroll
    for (int g = 0; g < 4; ++g) {
        f4 dva = *(const f4*)&dp[g*8];
        f4 dvb = *(const f4*)&dp[g*8 + 4];
        u8v xv = *(const u8v*)&xp[g*8];
#pragma unroll
        for (int j = 0; j < 8; ++j) {
            float dj = (j < 4) ? dva[j] : dvb[j-4];
            float dx = dj * us2f(xv[j]);
            f4 Bv = *(const f4*)&bp[(size_t)(g*8 + j) * 32];
            f2 djv = (f2){dj, dj};
            f2 e01 = djv * ac01, e23 = djv * ac23;
            f2 a01 = (f2){__expf(e01.x), __expf(e01.y)};
            f2 a23 = (f2){__expf(e23.x), __expf(e23.y)};
            f2 d01 = (f2){dx * Bv[0], dx * Bv[1]};
            f2 d23 = (f2){dx * Bv[2], dx * Bv[3]};
            P01 *= a01;  P23 *= a23;
            S01 = a01 * S01 + d01;
            S23 = a23 * S23 + d23;
        }
    }
    PSl[c][2*ng + 0] = (f4){P01.x, P01.y, S01.x, S01.y};
    PSl[c][2*ng + 1] = (f4){P23.x, P23.y, S23.x, S23.y};
    __syncthreads();

    // ---------------- inter-chunk prefix (serial over c2 < c) ----------------
    f2 h01 = (f2){0.f, 0.f}, h23 = (f2){0.f, 0.f};
    for (int c2 = 0; c2 < c; ++c2) {
        f4 ps0 = PSl[c2][2*ng + 0];
        f4 ps1 = PSl[c2][2*ng + 1];
        h01 = (f2){ps0[0], ps0[1]} * h01 + (f2){ps0[2], ps0[3]};
        h23 = (f2){ps1[0], ps1[1]} * h23 + (f2){ps1[2], ps1[3]};
    }

    // ---------------- pass 2: recompute a/d, emit y ----------------
#pragma unroll
    for (int g = 0; g < 4; ++g) {
        f4 dva = *(const f4*)&dp[g*8];
        f4 dvb = *(const f4*)&dp[g*8 + 4];
        u8v xv = *(const u8v*)&xp[g*8];
#pragma unroll
        for (int j = 0; j < 8; ++j) {
            float dj = (j < 4) ? dva[j] : dvb[j-4];
            float dx = dj * us2f(xv[j]);
            f4 Bv = *(const f4*)&bp[(size_t)(g*8 + j) * 32];
            f4 Cv = *(const f4*)&cp[(size_t)(g*8 + j) * 32];
            f2 djv = (f2){dj, dj};
            f2 e01 = djv * ac01, e23 = djv * ac23;
            f2 a01 = (f2){__expf(e01.x), __expf(e01.y)};
            f2 a23 = (f2){__expf(e23.x), __expf(e23.y)};
            f2 d01 = (f2){dx * Bv[0], dx * Bv[1]};
            f2 d23 = (f2){dx * Bv[2], dx * Bv[3]};
            h01 = a01 * h01 + d01;
            h23 = a23 * h23 + d23;
            float s = (h01.x * Cv[0] + h01.y * Cv[1])
                    + (h23.x * Cv[2] + h23.y * Cv[3]);
            s = sum4_quad(s);             // all 4 quad lanes hold the total
            int t = t0 + g*8 + j;
            if (ng == 0) ys[t + (t >> 5)] = s;
        }
    }
    __syncthreads();

    // ---------------- gated coalesced output ----------------
    {
        int i = tid * 8;                   // 128 threads x 8 t's
        int fi = i + (i >> 5);
        u8v ug = *(const u8v*)&g_t[cb0 + i];
        u8v uy;
#pragma unroll
        for (int k = 0; k < 8; ++k) {
            float gv = us2f(ug[k]);
            float yv = ys[fi + k] * gv * (1.f / (1.f + __expf(-gv)));
            uy[k] = f2us(yv);
        }
        *(u8v*)&y_t[cb0 + i] = uy;
    }
}

extern "C" void kernel_launch(void* const* d_in, const int* in_sizes, int n_in,
                              void* d_out, int out_size, void* d_ws, size_t ws_size,
                              hipStream_t stream)
{
    const float* x      = (const float*)d_in[0];
    const float* rms_w  = (const float*)d_in[1];
    const float* in_W   = (const float*)d_in[2];
    const float* in_b   = (const float*)d_in[3];
    const float* conv_w = (const float*)d_in[4];
    const float* conv_b = (const float*)d_in[5];
    const float* A_log  = (const float*)d_in[6];
    const float* dbc_W  = (const float*)d_in[7];
    const float* dbc_b  = (const float*)d_in[8];
    const float* dup_W  = (const float*)d_in[9];
    const float* dup_b  = (const float*)d_in[10];
    const float* out_W  = (const float*)d_in[11];
    const float* out_b  = (const float*)d_in[12];
    float* out = (float*)d_out;

    // ---- workspace layout (~83 MB; 89.3 MB proven available) ----
    float* ws      = (float*)d_ws;
    float* x1pre   = ws;                           // 16 MB fp32 [rows][D], dead after conv
    us* g_rm  = (us*)(x1pre + (size_t)ROWS*D_);    // 8 MB bf16 [rows][D], dead after conv
    us* g_t   = g_rm  + (size_t)ROWS*D_;           // 8 MB bf16 [d][rows]
    float* bct     = (float*)(g_t + (size_t)ROWS*D_); // 256 KB fp32 [rows][32] (B|C)
    float* delta_t = bct + (size_t)2*N_*ROWS;      // 16 MB fp32 [d][rows]
    us* hbf   = (us*)(delta_t + (size_t)ROWS*D_);  // 4 MB
    us* x1cb  = hbf   + (size_t)ROWS*DM_;          // 8 MB [rows][D], dead after dbc-GEMM
    us* x1tb  = x1cb  + (size_t)ROWS*D_;           // 8 MB [d][rows]
    us* dtrb  = x1tb  + (size_t)ROWS*D_;           // 0.5 MB [rows][DTR]
    us* inWt  = dtrb  + (size_t)ROWS*DTR_;         // 8 MB  [4096][1024]
    us* dbcWt = inWt  + (size_t)2*D_*DM_;          // 0.64 MB [160][2048]
    us* dupWt = dbcWt + (size_t)NDBC*D_;           // 0.5 MB [2048][128]
    us* outWt = dupWt + (size_t)D_*DTR_;           // 4 MB  [1024][2048]
    us* y_t   = (us*)x1pre;                        // alias (x1pre dead), [d][rows]
    us* ybf   = x1cb;                              // alias (x1cb dead), [rows][D]

    dim3 tb(32, 8);
    // 1. weight prep
    prep_weights<<<6720, tb, 0, stream>>>(in_W, out_W, dbc_W, dup_W,
                                          inWt, outWt, dbcWt, dupWt);
    // 2. fused rmsnorm -> hbf (bf16)
    rmshbf_kernel<<<ROWS, 256, 0, stream>>>(x, rms_w, hbf);
    // 3. fused in_proj: x1pre fp32 + g_rm bf16 (both row-major)  [2048 x 4096], K=1024
    mgemm<4,false><<<dim3(32, 16), 256, 0, stream>>>(
        hbf, inWt, in_b, x1pre, g_rm, nullptr, nullptr, ROWS, 2*D_, DM_);
    // 4. conv + silu -> x1cb + x1tb ; g_rm -> g_t transpose
    conv_silu_kernel<<<dim3(D_/32, ROWS/32), tb, 0, stream>>>(
        x1pre, g_rm, conv_w, conv_b, x1cb, x1tb, g_t);
    // 5. dbc = x1c @ dbc_W + dbc_b  [2048 x 160], K=2048
    //    -> bf16 aux (cols<128) + fp32 B/C into bct[rows][32]
    mgemm<3,false><<<dim3(2, 16), 256, 0, stream>>>(
        x1cb, dbcWt, dbc_b, nullptr, dtrb, nullptr, bct, ROWS, NDBC, D_);
    // 6. delta_t = softplus(dup_W^T @ dtr^T + dup_b)  [2048 x 2048], K=128
    mgemm<1,true><<<dim3(16, 16), 256, 0, stream>>>(
        dupWt, dtrb, dup_b, delta_t, nullptr, nullptr, nullptr, D_, ROWS, DTR_);
    // 7. chunked selective scan + gate -> y_t [d][rows]
    scan_block_kernel<<<B_*D_, 128, 0, stream>>>(delta_t, x1tb, bct, A_log, g_t, y_t);
    // 8. y_t -> ybf [rows][D]
    transpose_us<<<dim3(ROWS/32, D_/32), tb, 0, stream>>>(y_t, ybf, D_, ROWS);
    // 9. out = y @ out_W + out_b + residual   [2048 x 1024], K=2048
    mgemm<2,false><<<dim3(8, 16), 256, 0, stream>>>(
        ybf, outWt, out_b, out, nullptr, x, nullptr, ROWS, DM_, D_);
}

// Round 5
// 268.882 us; speedup vs baseline: 1.2621x; 1.1474x over previous
//
#include <hip/hip_runtime.h>
#include <math.h>

typedef unsigned short us;
typedef __attribute__((ext_vector_type(8))) short frag8;
typedef __attribute__((ext_vector_type(8))) unsigned short u8v;
typedef __attribute__((ext_vector_type(4))) float f4;
typedef __attribute__((ext_vector_type(2))) float f2;

#define B_   2
#define T_   1024
#define DM_  1024
#define D_   2048
#define N_   16
#define DTR_ 128
#define NDBC 160           // DTR + 2N
#define ROWS (B_*T_)       // 2048
#define EPS_ 1e-6f
#define NCH  32            // scan chunks per channel
#define CLEN (T_/NCH)      // 32 steps per chunk
#define KSPL 8             // split-K factor for dbc GEMM

__device__ __forceinline__ float us2f(us s){
    return __uint_as_float(((unsigned int)s) << 16);
}
__device__ __forceinline__ us f2us(float f){   // RTN-even fp32->bf16
    unsigned int u = __float_as_uint(f);
    return (us)((u + 0x7FFF + ((u >> 16) & 1)) >> 16);
}

// async global->LDS, 16B per lane. LDS dest is wave-uniform base + lane*16.
__device__ __forceinline__ void async16(const void* g, void* l){
    __builtin_amdgcn_global_load_lds(
        (const __attribute__((address_space(1))) void*)g,
        (__attribute__((address_space(3)))       void*)l, 16, 0, 0);
}

// one DPP accumulate step (dpp_ctrl must be a literal constant)
template<int CTRL>
__device__ __forceinline__ float dpp_add(float x){
    int t = __builtin_amdgcn_update_dpp(0, __float_as_int(x), CTRL, 0xF, 0xF, true);
    return x + __int_as_float(t);
}
// 4-lane (quad) sum via two quad_perm DPP adds; all 4 lanes get the total
__device__ __forceinline__ float sum4_quad(float x){
    x = dpp_add<0xB1>(x);   // quad_perm [1,0,3,2]
    x = dpp_add<0x4E>(x);   // quad_perm [2,3,0,1]
    return x;
}

// ---- combined weight prep: 4 matrices fp32 [R][C] -> bf16 [C][R] ----
__global__ __launch_bounds__(256) void prep_weights(
    const float* __restrict__ in_W,  const float* __restrict__ out_W,
    const float* __restrict__ dbc_W, const float* __restrict__ dup_W,
    us* __restrict__ inWt, us* __restrict__ outWt,
    us* __restrict__ dbcWt, us* __restrict__ dupWt)
{
    __shared__ us tile[32][33];
    int bid = blockIdx.x;
    const float* src; us* dst; int C, R, TX, rel;
    if (bid < 4096)      { src = in_W;  dst = inWt;  R = 1024; C = 4096; TX = 128; rel = bid; }
    else if (bid < 6144) { src = out_W; dst = outWt; R = 2048; C = 1024; TX = 32;  rel = bid - 4096; }
    else if (bid < 6464) { src = dbc_W; dst = dbcWt; R = 2048; C = 160;  TX = 5;   rel = bid - 6144; }
    else                 { src = dup_W; dst = dupWt; R = 128;  C = 2048; TX = 64;  rel = bid - 6464; }
    int c0 = (rel % TX) * 32, r0 = (rel / TX) * 32;
    int tx = threadIdx.x, ty = threadIdx.y;   // 32 x 8
    for (int i = ty; i < 32; i += 8)
        tile[i][tx] = f2us(src[(size_t)(r0 + i) * C + c0 + tx]);
    __syncthreads();
    for (int i = ty; i < 32; i += 8)
        dst[(size_t)(c0 + i) * R + r0 + tx] = tile[tx][i];
}

// ------------- bf16 [R][C] -> bf16 [C][R] (dims multiples of 32) -------------
__global__ __launch_bounds__(256) void transpose_us(const us* __restrict__ in,
                                                    us* __restrict__ out, int R, int C)
{
    __shared__ us tile[32][33];
    int c0 = blockIdx.x * 32, r0 = blockIdx.y * 32;
    int tx = threadIdx.x, ty = threadIdx.y;   // 32 x 8
    for (int i = ty; i < 32; i += 8)
        tile[i][tx] = in[(size_t)(r0 + i) * C + c0 + tx];
    __syncthreads();
    for (int i = ty; i < 32; i += 8)
        out[(size_t)(c0 + i) * R + r0 + tx] = tile[tx][i];
}

// ---------------- fused RMSNorm -> bf16 h, one block per row ----------------
__global__ __launch_bounds__(256) void rmshbf_kernel(const float* __restrict__ x,
                                                     const float* __restrict__ rms_w,
                                                     us* __restrict__ hbf)
{
    const int row = blockIdx.x;
    const float* xr = x + (size_t)row * DM_;
    const int tid = threadIdx.x;
    float vals[4], ss = 0.f;
#pragma unroll
    for (int i = 0; i < 4; ++i) { vals[i] = xr[tid + i*256]; ss += vals[i]*vals[i]; }
#pragma unroll
    for (int off = 32; off >= 1; off >>= 1) ss += __shfl_xor(ss, off, 64);
    __shared__ float red[4];
    if ((tid & 63) == 0) red[tid >> 6] = ss;
    __syncthreads();
    float scale = rsqrtf((red[0]+red[1]+red[2]+red[3]) / (float)DM_ + EPS_);
#pragma unroll
    for (int i = 0; i < 4; ++i)
        hbf[(size_t)row * DM_ + tid + i*256] = f2us(vals[i] * scale * rms_w[tid + i*256]);
}

// ---------- MFMA GEMM: C[M,N] = A[M,K](bf16) * Bt[N,K](bf16)^T + bias --------
// 128x128 tile / 4 waves; wave 64x64 via 4x4 mfma_f32_16x16x32_bf16.
// ld = row stride of A and Bt (elements); K = K-range this block loops over.
// EPI 5 (split-K): blockIdx.z selects K-slice, raw partial (no bias) written
// to Cf + z*M*N. Other EPIs as before.
template<int EPI, bool RB>
__global__ __launch_bounds__(256) void mgemm(
    const us*    __restrict__ A,     // [M][ld]
    const us*    __restrict__ Bt,    // [N][ld]
    const float* __restrict__ bias,
    float*       __restrict__ Cf,
    us*          __restrict__ Caux,
    const float* __restrict__ resid, // EPI==2
    float*       __restrict__ bct,   // EPI==3
    int M, int N, int K, int ld)
{
    __shared__ us As[128*64];
    __shared__ us Bs[128*64];
    const int tid = threadIdx.x;
    const int bm = blockIdx.y * 128;
    const int bn = blockIdx.x * 128;
    const int w = tid >> 6, lane = tid & 63;
    const int wr = w >> 1, wc = w & 1;
    const int m16 = lane & 15, quad = lane >> 4;

    const us* Ak = A;
    const us* Bk = Bt;
    if constexpr (EPI == 5) {
        const size_t koff = (size_t)blockIdx.z * K;
        Ak += koff; Bk += koff;
        Cf += (size_t)blockIdx.z * (size_t)M * N;
    }

    f4 acc[4][4];
#pragma unroll
    for (int i = 0; i < 4; ++i)
#pragma unroll
        for (int j = 0; j < 4; ++j)
            acc[i][j] = (f4){0.f, 0.f, 0.f, 0.f};

    for (int k0 = 0; k0 < K; k0 += 64) {
        __syncthreads();   // prior iter's frag reads done before overwrite
#pragma unroll
        for (int q = 0; q < 4; ++q) {
            int cb = (w*4 + q)*64 + lane;       // 16B-chunk id 0..1023
            int row = cb >> 3, c8 = (cb & 7)*8;
            async16(Ak + (size_t)(bm + row) * ld + k0 + c8, &As[cb*8]);
            async16(Bk + (size_t)(bn + row) * ld + k0 + c8, &Bs[cb*8]);
        }
        __syncthreads();   // vmcnt(0) drained here -> LDS valid
#pragma unroll
        for (int ks = 0; ks < 64; ks += 32) {
            frag8 af[4], bfr[4];
#pragma unroll
            for (int i = 0; i < 4; ++i)
                af[i] = *(const frag8*)&As[(wr*64 + i*16 + m16)*64 + ks + quad*8];
#pragma unroll
            for (int j = 0; j < 4; ++j)
                bfr[j] = *(const frag8*)&Bs[(wc*64 + j*16 + m16)*64 + ks + quad*8];
#pragma unroll
            for (int i = 0; i < 4; ++i)
#pragma unroll
                for (int j = 0; j < 4; ++j)
                    acc[i][j] = __builtin_amdgcn_mfma_f32_16x16x32_bf16(af[i], bfr[j], acc[i][j], 0, 0, 0);
        }
    }

#pragma unroll
    for (int i = 0; i < 4; ++i) {
#pragma unroll
        for (int j = 0; j < 4; ++j) {
            int col = bn + wc*64 + j*16 + m16;
            if (col >= N) continue;
            float bvc = (RB || EPI == 5) ? 0.f : bias[col];
#pragma unroll
            for (int r = 0; r < 4; ++r) {
                int row = bm + wr*64 + i*16 + quad*4 + r;
                float v = acc[i][j][r] + (EPI == 5 ? 0.f : (RB ? bias[row] : bvc));
                if constexpr (EPI == 1) {
                    v = fmaxf(v, 0.f) + __logf(1.f + __expf(-fabsf(v)));
                    Cf[(size_t)row * N + col] = v;
                } else if constexpr (EPI == 2) {
                    v += resid[(size_t)row * N + col];
                    Cf[(size_t)row * N + col] = v;
                } else if constexpr (EPI == 3) {
                    if (col < DTR_) Caux[(size_t)row * DTR_ + col] = f2us(v);
                    else            bct [(size_t)row * 32 + (col - DTR_)] = v;
                } else if constexpr (EPI == 4) {
                    if (col < D_) Cf  [(size_t)row * D_ + col]        = v;
                    else          Caux[(size_t)row * D_ + (col - D_)] = f2us(v);
                } else {   // EPI 0 and EPI 5 (partial)
                    Cf[(size_t)row * N + col] = v;
                }
            }
        }
    }
}

// ---- split-K reduce for dbc: sum 8 partials + bias -> dtrb bf16 + bct fp32 ----
__global__ __launch_bounds__(256) void dbc_reduce(
    const float* __restrict__ part,   // [KSPL][ROWS][NDBC]
    const float* __restrict__ bias,
    us*    __restrict__ dtrb,         // [ROWS][DTR]
    float* __restrict__ bct)          // [ROWS][32]
{
    int idx = blockIdx.x * 256 + threadIdx.x;   // < ROWS*NDBC
    int row = idx / NDBC, col = idx - row * NDBC;
    float v = bias[col];
#pragma unroll
    for (int z = 0; z < KSPL; ++z)
        v += part[(size_t)z * ROWS * NDBC + idx];
    if (col < DTR_) dtrb[(size_t)row * DTR_ + col] = f2us(v);
    else            bct [(size_t)row * 32 + (col - DTR_)] = v;
}

// --- depthwise causal conv (K=4) + SiLU, dual-layout x1 out + g transpose ---
__global__ __launch_bounds__(256) void conv_silu_kernel(
    const float* __restrict__ x1pre,
    const us*    __restrict__ g_rm,
    const float* __restrict__ cw,
    const float* __restrict__ cb,
    us*          __restrict__ x1cb,
    us*          __restrict__ x1tb,
    us*          __restrict__ g_t)
{
    __shared__ us tileX[32][33];
    __shared__ us tileG[32][33];
    const int tx = threadIdx.x, ty = threadIdx.y;   // 32 x 8
    const int d0 = blockIdx.x * 32, r0 = blockIdx.y * 32;
    const int d = d0 + tx;
    const float w0 = cw[d*4+0], w1 = cw[d*4+1], w2 = cw[d*4+2], w3 = cw[d*4+3];
    const float bias = cb[d];
    for (int i = ty; i < 32; i += 8) {
        int row = r0 + i;
        int t = row & (T_ - 1);
        const float* base = x1pre + (size_t)row * D_ + d;
        float acc = bias;
        acc = fmaf(w3, base[0], acc);
        if (t >= 1) acc = fmaf(w2, base[-D_],   acc);
        if (t >= 2) acc = fmaf(w1, base[-2*D_], acc);
        if (t >= 3) acc = fmaf(w0, base[-3*D_], acc);
        float sg = 1.f / (1.f + __expf(-acc));
        us uv = f2us(acc * sg);
        x1cb[(size_t)row * D_ + d] = uv;
        tileX[i][tx] = uv;
        tileG[i][tx] = g_rm[(size_t)row * D_ + d];
    }
    __syncthreads();
    for (int i = ty; i < 32; i += 8) {
        x1tb[(size_t)(d0 + i) * ROWS + r0 + tx] = tileX[tx][i];
        g_t [(size_t)(d0 + i) * ROWS + r0 + tx] = tileG[tx][i];
    }
}

// ------- chunked selective scan + gate, TWO channels per block ---------------
// v6: B/C depend only on (b,t,n) -- pairing channels (d0, d0+1) in the same
// thread shares every Bv/Cv load + address chain between two INDEPENDENT
// recurrence chains (2x ILP for the latency-bound v5). 128 threads =
// (chunk c 0..31) x (state-group ng 0..3); each thread: 4 states x 2 channels.
// delta/x direct from global (f4/16B); recompute in pass 2 (no reg carry --
// the v2-v4 lesson).
__global__ __launch_bounds__(128, 4) void scan_block_kernel(
    const float* __restrict__ delta_t,
    const us*    __restrict__ x1tb,
    const float* __restrict__ bct,    // [rows][32]: [0:16]=B_n, [16:32]=C_n
    const float* __restrict__ A_log,
    const us*    __restrict__ g_t,
    us*          __restrict__ y_t)
{
    __shared__ float ysA[T_ + NCH];   // swizzle f(t) = t + (t>>5)
    __shared__ float ysB[T_ + NCH];
    __shared__ f4 PSl[2][NCH][9];     // [ch][c][2ng+(0,1)]; +1 pad col

    const int tid = threadIdx.x;       // 128
    const int pr = blockIdx.x & (D_/2 - 1);
    const int b  = blockIdx.x >> 10;
    const int d0 = pr * 2;
    const int ng = tid & 3;            // states 4ng .. 4ng+3
    const int c  = tid >> 2;           // chunk 0..31
    const size_t rb  = (size_t)b * T_;
    const size_t cb0 = (size_t)d0 * ROWS + rb;   // ch0; ch1 at +ROWS
    const int t0 = c * CLEN;

    f4 al0 = *(const f4*)&A_log[d0 * N_ + ng * 4];
    f4 al1 = *(const f4*)&A_log[(d0 + 1) * N_ + ng * 4];
    const f2 aA01 = (f2){-__expf(al0[0]), -__expf(al0[1])};
    const f2 aA23 = (f2){-__expf(al0[2]), -__expf(al0[3])};
    const f2 aB01 = (f2){-__expf(al1[0]), -__expf(al1[1])};
    const f2 aB23 = (f2){-__expf(al1[2]), -__expf(al1[3])};

    const float* __restrict__ dpA = delta_t + cb0 + t0;
    const float* __restrict__ dpB = dpA + ROWS;
    const us*    __restrict__ xpA = x1tb + cb0 + t0;
    const us*    __restrict__ xpB = xpA + ROWS;
    const float* __restrict__ bp = bct + (size_t)(rb + t0) * 32 + ng * 4;
    const float* __restrict__ cp = bp + 16;

    // ---------------- pass 1: per-chunk (P, S), both channels ----------------
    f2 PA01={1.f,1.f}, PA23={1.f,1.f}, SA01={0.f,0.f}, SA23={0.f,0.f};
    f2 PB01={1.f,1.f}, PB23={1.f,1.f}, SB01={0.f,0.f}, SB23={0.f,0.f};
#pragma unroll
    for (int g = 0; g < 4; ++g) {
        f4 dA0 = *(const f4*)&dpA[g*8], dA1 = *(const f4*)&dpA[g*8 + 4];
        f4 dB0 = *(const f4*)&dpB[g*8], dB1 = *(const f4*)&dpB[g*8 + 4];
        u8v xA = *(const u8v*)&xpA[g*8];
        u8v xB = *(const u8v*)&xpB[g*8];
#pragma unroll
        for (int j = 0; j < 8; ++j) {
            float djA = (j < 4) ? dA0[j] : dA1[j-4];
            float djB = (j < 4) ? dB0[j] : dB1[j-4];
            f4 Bv = *(const f4*)&bp[(size_t)(g*8 + j) * 32];
            float dxA = djA * us2f(xA[j]);
            float dxB = djB * us2f(xB[j]);
            f2 jA = (f2){djA, djA}, jB = (f2){djB, djB};
            f2 eA01 = jA*aA01, eA23 = jA*aA23;
            f2 eB01 = jB*aB01, eB23 = jB*aB23;
            f2 xA01 = (f2){__expf(eA01.x), __expf(eA01.y)};
            f2 xA23 = (f2){__expf(eA23.x), __expf(eA23.y)};
            f2 xB01 = (f2){__expf(eB01.x), __expf(eB01.y)};
            f2 xB23 = (f2){__expf(eB23.x), __expf(eB23.y)};
            PA01 *= xA01; PA23 *= xA23; PB01 *= xB01; PB23 *= xB23;
            SA01 = xA01*SA01 + (f2){dxA*Bv[0], dxA*Bv[1]};
            SA23 = xA23*SA23 + (f2){dxA*Bv[2], dxA*Bv[3]};
            SB01 = xB01*SB01 + (f2){dxB*Bv[0], dxB*Bv[1]};
            SB23 = xB23*SB23 + (f2){dxB*Bv[2], dxB*Bv[3]};
        }
    }
    PSl[0][c][2*ng+0] = (f4){PA01.x,PA01.y,SA01.x,SA01.y};
    PSl[0][c][2*ng+1] = (f4){PA23.x,PA23.y,SA23.x,SA23.y};
    PSl[1][c][2*ng+0] = (f4){PB01.x,PB01.y,SB01.x,SB01.y};
    PSl[1][c][2*ng+1] = (f4){PB23.x,PB23.y,SB23.x,SB23.y};
    __syncthreads();

    // ---------------- inter-chunk prefix (serial over c2 < c) ----------------
    f2 hA01={0.f,0.f}, hA23={0.f,0.f}, hB01={0.f,0.f}, hB23={0.f,0.f};
    for (int c2 = 0; c2 < c; ++c2) {
        f4 p0 = PSl[0][c2][2*ng+0], p1 = PSl[0][c2][2*ng+1];
        f4 q0 = PSl[1][c2][2*ng+0], q1 = PSl[1][c2][2*ng+1];
        hA01 = (f2){p0[0],p0[1]}*hA01 + (f2){p0[2],p0[3]};
        hA23 = (f2){p1[0],p1[1]}*hA23 + (f2){p1[2],p1[3]};
        hB01 = (f2){q0[0],q0[1]}*hB01 + (f2){q0[2],q0[3]};
        hB23 = (f2){q1[0],q1[1]}*hB23 + (f2){q1[2],q1[3]};
    }

    // ---------------- pass 2: recompute a/d, emit y (both channels) ----------
#pragma unroll
    for (int g = 0; g < 4; ++g) {
        f4 dA0 = *(const f4*)&dpA[g*8], dA1 = *(const f4*)&dpA[g*8 + 4];
        f4 dB0 = *(const f4*)&dpB[g*8], dB1 = *(const f4*)&dpB[g*8 + 4];
        u8v xA = *(const u8v*)&xpA[g*8];
        u8v xB = *(const u8v*)&xpB[g*8];
#pragma unroll
        for (int j = 0; j < 8; ++j) {
            float djA = (j < 4) ? dA0[j] : dA1[j-4];
            float djB = (j < 4) ? dB0[j] : dB1[j-4];
            f4 Bv = *(const f4*)&bp[(size_t)(g*8 + j) * 32];
            f4 Cv = *(const f4*)&cp[(size_t)(g*8 + j) * 32];
            float dxA = djA * us2f(xA[j]);
            float dxB = djB * us2f(xB[j]);
            f2 jA = (f2){djA, djA}, jB = (f2){djB, djB};
            f2 eA01 = jA*aA01, eA23 = jA*aA23;
            f2 eB01 = jB*aB01, eB23 = jB*aB23;
            f2 xA01 = (f2){__expf(eA01.x), __expf(eA01.y)};
            f2 xA23 = (f2){__expf(eA23.x), __expf(eA23.y)};
            f2 xB01 = (f2){__expf(eB01.x), __expf(eB01.y)};
            f2 xB23 = (f2){__expf(eB23.x), __expf(eB23.y)};
            hA01 = xA01*hA01 + (f2){dxA*Bv[0], dxA*Bv[1]};
            hA23 = xA23*hA23 + (f2){dxA*Bv[2], dxA*Bv[3]};
            hB01 = xB01*hB01 + (f2){dxB*Bv[0], dxB*Bv[1]};
            hB23 = xB23*hB23 + (f2){dxB*Bv[2], dxB*Bv[3]};
            float sA = (hA01.x*Cv[0] + hA01.y*Cv[1]) + (hA23.x*Cv[2] + hA23.y*Cv[3]);
            float sB = (hB01.x*Cv[0] + hB01.y*Cv[1]) + (hB23.x*Cv[2] + hB23.y*Cv[3]);
            sA = sum4_quad(sA);
            sB = sum4_quad(sB);
            int t = t0 + g*8 + j;
            if (ng == 0) { ysA[t + (t >> 5)] = sA; ysB[t + (t >> 5)] = sB; }
        }
    }
    __syncthreads();

    // ---------------- gated coalesced output, both channels ----------------
    {
        int i = tid * 8;                   // 128 threads x 8 t's per channel
        int fi = i + (i >> 5);
        u8v ugA = *(const u8v*)&g_t[cb0 + i];
        u8v ugB = *(const u8v*)&g_t[cb0 + ROWS + i];
        u8v uyA, uyB;
#pragma unroll
        for (int k = 0; k < 8; ++k) {
            float gA = us2f(ugA[k]), gB = us2f(ugB[k]);
            uyA[k] = f2us(ysA[fi + k] * gA * (1.f / (1.f + __expf(-gA))));
            uyB[k] = f2us(ysB[fi + k] * gB * (1.f / (1.f + __expf(-gB))));
        }
        *(u8v*)&y_t[cb0 + i] = uyA;
        *(u8v*)&y_t[cb0 + ROWS + i] = uyB;
    }
}

extern "C" void kernel_launch(void* const* d_in, const int* in_sizes, int n_in,
                              void* d_out, int out_size, void* d_ws, size_t ws_size,
                              hipStream_t stream)
{
    const float* x      = (const float*)d_in[0];
    const float* rms_w  = (const float*)d_in[1];
    const float* in_W   = (const float*)d_in[2];
    const float* in_b   = (const float*)d_in[3];
    const float* conv_w = (const float*)d_in[4];
    const float* conv_b = (const float*)d_in[5];
    const float* A_log  = (const float*)d_in[6];
    const float* dbc_W  = (const float*)d_in[7];
    const float* dbc_b  = (const float*)d_in[8];
    const float* dup_W  = (const float*)d_in[9];
    const float* dup_b  = (const float*)d_in[10];
    const float* out_W  = (const float*)d_in[11];
    const float* out_b  = (const float*)d_in[12];
    float* out = (float*)d_out;

    // ---- workspace layout (~83 MB; 89.3 MB proven available) ----
    float* ws      = (float*)d_ws;
    float* x1pre   = ws;                           // 16 MB fp32 [rows][D], dead after conv
    us* g_rm  = (us*)(x1pre + (size_t)ROWS*D_);    // 8 MB bf16 [rows][D], dead after conv
    us* g_t   = g_rm  + (size_t)ROWS*D_;           // 8 MB bf16 [d][rows]
    float* bct     = (float*)(g_t + (size_t)ROWS*D_); // 256 KB fp32 [rows][32] (B|C)
    float* delta_t = bct + (size_t)2*N_*ROWS;      // 16 MB fp32 [d][rows]
    us* hbf   = (us*)(delta_t + (size_t)ROWS*D_);  // 4 MB
    us* x1cb  = hbf   + (size_t)ROWS*DM_;          // 8 MB [rows][D], dead after dbc-GEMM
    us* x1tb  = x1cb  + (size_t)ROWS*D_;           // 8 MB [d][rows]
    us* dtrb  = x1tb  + (size_t)ROWS*D_;           // 0.5 MB [rows][DTR]
    us* inWt  = dtrb  + (size_t)ROWS*DTR_;         // 8 MB  [4096][1024]
    us* dbcWt = inWt  + (size_t)2*D_*DM_;          // 0.64 MB [160][2048]
    us* dupWt = dbcWt + (size_t)NDBC*D_;           // 0.5 MB [2048][128]
    us* outWt = dupWt + (size_t)D_*DTR_;           // 4 MB  [1024][2048]
    float* dbcPart = x1pre;                        // alias (x1pre dead): 10.5 MB [8][2048][160]
    us* y_t   = (us*)x1pre;                        // alias (partials dead after reduce)
    us* ybf   = x1cb;                              // alias (x1cb dead), [rows][D]

    dim3 tb(32, 8);
    // 1. weight prep
    prep_weights<<<6720, tb, 0, stream>>>(in_W, out_W, dbc_W, dup_W,
                                          inWt, outWt, dbcWt, dupWt);
    // 2. fused rmsnorm -> hbf (bf16)
    rmshbf_kernel<<<ROWS, 256, 0, stream>>>(x, rms_w, hbf);
    // 3. fused in_proj: x1pre fp32 + g_rm bf16 (both row-major)  [2048 x 4096], K=1024
    mgemm<4,false><<<dim3(32, 16), 256, 0, stream>>>(
        hbf, inWt, in_b, x1pre, g_rm, nullptr, nullptr, ROWS, 2*D_, DM_, DM_);
    // 4. conv + silu -> x1cb + x1tb ; g_rm -> g_t transpose
    conv_silu_kernel<<<dim3(D_/32, ROWS/32), tb, 0, stream>>>(
        x1pre, g_rm, conv_w, conv_b, x1cb, x1tb, g_t);
    // 5. dbc partials, split-K x8: [2048 x 160], K=2048/8=256 per slice
    mgemm<5,false><<<dim3(2, 16, KSPL), 256, 0, stream>>>(
        x1cb, dbcWt, nullptr, dbcPart, nullptr, nullptr, nullptr,
        ROWS, NDBC, D_/KSPL, D_);
    // 5b. reduce partials + bias -> dtrb bf16 + bct fp32
    dbc_reduce<<<ROWS*NDBC/256, 256, 0, stream>>>(dbcPart, dbc_b, dtrb, bct);
    // 6. delta_t = softplus(dup_W^T @ dtr^T + dup_b)  [2048 x 2048], K=128
    mgemm<1,true><<<dim3(16, 16), 256, 0, stream>>>(
        dupWt, dtrb, dup_b, delta_t, nullptr, nullptr, nullptr, D_, ROWS, DTR_, DTR_);
    // 7. paired-channel selective scan + gate -> y_t [d][rows]
    scan_block_kernel<<<B_*D_/2, 128, 0, stream>>>(delta_t, x1tb, bct, A_log, g_t, y_t);
    // 8. y_t -> ybf [rows][D]
    transpose_us<<<dim3(ROWS/32, D_/32), tb, 0, stream>>>(y_t, ybf, D_, ROWS);
    // 9. out = y @ out_W + out_b + residual   [2048 x 1024], K=2048
    mgemm<2,false><<<dim3(8, 16), 256, 0, stream>>>(
        ybf, outWt, out_b, out, nullptr, x, nullptr, ROWS, DM_, D_, D_);
}

// Round 7
// 251.282 us; speedup vs baseline: 1.3505x; 1.0700x over previous
//
#include <hip/hip_runtime.h>
#include <math.h>

typedef unsigned short us;
typedef __attribute__((ext_vector_type(8))) short frag8;
typedef __attribute__((ext_vector_type(8))) unsigned short u8v;
typedef __attribute__((ext_vector_type(4))) float f4;
typedef __attribute__((ext_vector_type(2))) float f2;

#define B_   2
#define T_   1024
#define DM_  1024
#define D_   2048
#define N_   16
#define DTR_ 128
#define NDBC 160           // DTR + 2N
#define ROWS (B_*T_)       // 2048
#define EPS_ 1e-6f
#define NCH  32            // scan chunks per channel
#define CLEN (T_/NCH)      // 32 steps per chunk
#define KSPL 8             // split-K factor for dbc GEMM
#define OSPL 4             // split-K factor for out-proj GEMM

__device__ __forceinline__ float us2f(us s){
    return __uint_as_float(((unsigned int)s) << 16);
}
__device__ __forceinline__ us f2us(float f){   // RTN-even fp32->bf16
    unsigned int u = __float_as_uint(f);
    return (us)((u + 0x7FFF + ((u >> 16) & 1)) >> 16);
}

// async global->LDS, 16B per lane. LDS dest is wave-uniform base + lane*16.
__device__ __forceinline__ void async16(const void* g, void* l){
    __builtin_amdgcn_global_load_lds(
        (const __attribute__((address_space(1))) void*)g,
        (__attribute__((address_space(3)))       void*)l, 16, 0, 0);
}

// one DPP accumulate step (dpp_ctrl must be a literal constant)
template<int CTRL>
__device__ __forceinline__ float dpp_add(float x){
    int t = __builtin_amdgcn_update_dpp(0, __float_as_int(x), CTRL, 0xF, 0xF, true);
    return x + __int_as_float(t);
}
// 4-lane (quad) sum via two quad_perm DPP adds; all 4 lanes get the total
__device__ __forceinline__ float sum4_quad(float x){
    x = dpp_add<0xB1>(x);   // quad_perm [1,0,3,2]
    x = dpp_add<0x4E>(x);   // quad_perm [2,3,0,1]
    return x;
}

// ---- combined weight prep: 4 matrices fp32 [R][C] -> bf16 [C][R] ----
__global__ __launch_bounds__(256) void prep_weights(
    const float* __restrict__ in_W,  const float* __restrict__ out_W,
    const float* __restrict__ dbc_W, const float* __restrict__ dup_W,
    us* __restrict__ inWt, us* __restrict__ outWt,
    us* __restrict__ dbcWt, us* __restrict__ dupWt)
{
    __shared__ us tile[32][33];
    int bid = blockIdx.x;
    const float* src; us* dst; int C, R, TX, rel;
    if (bid < 4096)      { src = in_W;  dst = inWt;  R = 1024; C = 4096; TX = 128; rel = bid; }
    else if (bid < 6144) { src = out_W; dst = outWt; R = 2048; C = 1024; TX = 32;  rel = bid - 4096; }
    else if (bid < 6464) { src = dbc_W; dst = dbcWt; R = 2048; C = 160;  TX = 5;   rel = bid - 6144; }
    else                 { src = dup_W; dst = dupWt; R = 128;  C = 2048; TX = 64;  rel = bid - 6464; }
    int c0 = (rel % TX) * 32, r0 = (rel / TX) * 32;
    int tx = threadIdx.x, ty = threadIdx.y;   // 32 x 8
    for (int i = ty; i < 32; i += 8)
        tile[i][tx] = f2us(src[(size_t)(r0 + i) * C + c0 + tx]);
    __syncthreads();
    for (int i = ty; i < 32; i += 8)
        dst[(size_t)(c0 + i) * R + r0 + tx] = tile[tx][i];
}

// ------------- bf16 [R][C] -> bf16 [C][R] (dims multiples of 32) -------------
__global__ __launch_bounds__(256) void transpose_us(const us* __restrict__ in,
                                                    us* __restrict__ out, int R, int C)
{
    __shared__ us tile[32][33];
    int c0 = blockIdx.x * 32, r0 = blockIdx.y * 32;
    int tx = threadIdx.x, ty = threadIdx.y;   // 32 x 8
    for (int i = ty; i < 32; i += 8)
        tile[i][tx] = in[(size_t)(r0 + i) * C + c0 + tx];
    __syncthreads();
    for (int i = ty; i < 32; i += 8)
        out[(size_t)(c0 + i) * R + r0 + tx] = tile[tx][i];
}

// ---------------- fused RMSNorm -> bf16 h, one block per row ----------------
__global__ __launch_bounds__(256) void rmshbf_kernel(const float* __restrict__ x,
                                                     const float* __restrict__ rms_w,
                                                     us* __restrict__ hbf)
{
    const int row = blockIdx.x;
    const float* xr = x + (size_t)row * DM_;
    const int tid = threadIdx.x;
    float vals[4], ss = 0.f;
#pragma unroll
    for (int i = 0; i < 4; ++i) { vals[i] = xr[tid + i*256]; ss += vals[i]*vals[i]; }
#pragma unroll
    for (int off = 32; off >= 1; off >>= 1) ss += __shfl_xor(ss, off, 64);
    __shared__ float red[4];
    if ((tid & 63) == 0) red[tid >> 6] = ss;
    __syncthreads();
    float scale = rsqrtf((red[0]+red[1]+red[2]+red[3]) / (float)DM_ + EPS_);
#pragma unroll
    for (int i = 0; i < 4; ++i)
        hbf[(size_t)row * DM_ + tid + i*256] = f2us(vals[i] * scale * rms_w[tid + i*256]);
}

// ---------- MFMA GEMM: C[M,N] = A[M,K](bf16) * Bt[N,K](bf16)^T + bias --------
// 128x128 tile / 4 waves; wave 64x64 via 4x4 mfma_f32_16x16x32_bf16.
// ld = row stride of A and Bt (elements); K = K-range this block loops over.
// EPI 5 (split-K): blockIdx.z selects K-slice, raw partial (no bias) written
// to Cf + z*M*N. Other EPIs as before.
template<int EPI, bool RB>
__global__ __launch_bounds__(256) void mgemm(
    const us*    __restrict__ A,     // [M][ld]
    const us*    __restrict__ Bt,    // [N][ld]
    const float* __restrict__ bias,
    float*       __restrict__ Cf,
    us*          __restrict__ Caux,
    const float* __restrict__ resid, // EPI==2
    float*       __restrict__ bct,   // EPI==3
    int M, int N, int K, int ld)
{
    __shared__ us As[128*64];
    __shared__ us Bs[128*64];
    const int tid = threadIdx.x;
    const int bm = blockIdx.y * 128;
    const int bn = blockIdx.x * 128;
    const int w = tid >> 6, lane = tid & 63;
    const int wr = w >> 1, wc = w & 1;
    const int m16 = lane & 15, quad = lane >> 4;

    const us* Ak = A;
    const us* Bk = Bt;
    if constexpr (EPI == 5) {
        const size_t koff = (size_t)blockIdx.z * K;
        Ak += koff; Bk += koff;
        Cf += (size_t)blockIdx.z * (size_t)M * N;
    }

    f4 acc[4][4];
#pragma unroll
    for (int i = 0; i < 4; ++i)
#pragma unroll
        for (int j = 0; j < 4; ++j)
            acc[i][j] = (f4){0.f, 0.f, 0.f, 0.f};

    for (int k0 = 0; k0 < K; k0 += 64) {
        __syncthreads();   // prior iter's frag reads done before overwrite
#pragma unroll
        for (int q = 0; q < 4; ++q) {
            int cb = (w*4 + q)*64 + lane;       // 16B-chunk id 0..1023
            int row = cb >> 3, c8 = (cb & 7)*8;
            async16(Ak + (size_t)(bm + row) * ld + k0 + c8, &As[cb*8]);
            async16(Bk + (size_t)(bn + row) * ld + k0 + c8, &Bs[cb*8]);
        }
        __syncthreads();   // vmcnt(0) drained here -> LDS valid
#pragma unroll
        for (int ks = 0; ks < 64; ks += 32) {
            frag8 af[4], bfr[4];
#pragma unroll
            for (int i = 0; i < 4; ++i)
                af[i] = *(const frag8*)&As[(wr*64 + i*16 + m16)*64 + ks + quad*8];
#pragma unroll
            for (int j = 0; j < 4; ++j)
                bfr[j] = *(const frag8*)&Bs[(wc*64 + j*16 + m16)*64 + ks + quad*8];
#pragma unroll
            for (int i = 0; i < 4; ++i)
#pragma unroll
                for (int j = 0; j < 4; ++j)
                    acc[i][j] = __builtin_amdgcn_mfma_f32_16x16x32_bf16(af[i], bfr[j], acc[i][j], 0, 0, 0);
        }
    }

#pragma unroll
    for (int i = 0; i < 4; ++i) {
#pragma unroll
        for (int j = 0; j < 4; ++j) {
            int col = bn + wc*64 + j*16 + m16;
            if (col >= N) continue;
            float bvc = (RB || EPI == 5) ? 0.f : bias[col];
#pragma unroll
            for (int r = 0; r < 4; ++r) {
                int row = bm + wr*64 + i*16 + quad*4 + r;
                float v = acc[i][j][r] + (EPI == 5 ? 0.f : (RB ? bias[row] : bvc));
                if constexpr (EPI == 1) {
                    v = fmaxf(v, 0.f) + __logf(1.f + __expf(-fabsf(v)));
                    Cf[(size_t)row * N + col] = v;
                } else if constexpr (EPI == 2) {
                    v += resid[(size_t)row * N + col];
                    Cf[(size_t)row * N + col] = v;
                } else if constexpr (EPI == 3) {
                    if (col < DTR_) Caux[(size_t)row * DTR_ + col] = f2us(v);
                    else            bct [(size_t)row * 32 + (col - DTR_)] = v;
                } else if constexpr (EPI == 4) {
                    if (col < D_) Cf  [(size_t)row * D_ + col]        = v;
                    else          Caux[(size_t)row * D_ + (col - D_)] = f2us(v);
                } else {   // EPI 0 and EPI 5 (partial)
                    Cf[(size_t)row * N + col] = v;
                }
            }
        }
    }
}

// ---- split-K reduce for dbc: sum 8 partials + bias -> dtrb bf16 + bct fp32 ----
__global__ __launch_bounds__(256) void dbc_reduce(
    const float* __restrict__ part,   // [KSPL][ROWS][NDBC]
    const float* __restrict__ bias,
    us*    __restrict__ dtrb,         // [ROWS][DTR]
    float* __restrict__ bct)          // [ROWS][32]
{
    int idx = blockIdx.x * 256 + threadIdx.x;   // < ROWS*NDBC
    int row = idx / NDBC, col = idx - row * NDBC;
    float v = bias[col];
#pragma unroll
    for (int z = 0; z < KSPL; ++z)
        v += part[(size_t)z * ROWS * NDBC + idx];
    if (col < DTR_) dtrb[(size_t)row * DTR_ + col] = f2us(v);
    else            bct [(size_t)row * 32 + (col - DTR_)] = v;
}

// ---- split-K reduce for out-proj: sum 4 partials + bias + residual ----
__global__ __launch_bounds__(256) void out_reduce(
    const float* __restrict__ part,   // [OSPL][ROWS][DM_]
    const float* __restrict__ bias,   // [DM_]
    const float* __restrict__ resid,  // [ROWS][DM_]
    float* __restrict__ out)
{
    int idx = (blockIdx.x * 256 + threadIdx.x) * 4;  // element index, f4 chunks
    int col = idx & (DM_ - 1);
    f4 v = *(const f4*)&bias[col];
    v += *(const f4*)&resid[idx];
#pragma unroll
    for (int z = 0; z < OSPL; ++z)
        v += *(const f4*)&part[(size_t)z * ROWS * DM_ + idx];
    *(f4*)&out[idx] = v;
}

// --- depthwise causal conv (K=4) + SiLU, dual-layout x1 out + g transpose ---
__global__ __launch_bounds__(256) void conv_silu_kernel(
    const float* __restrict__ x1pre,
    const us*    __restrict__ g_rm,
    const float* __restrict__ cw,
    const float* __restrict__ cb,
    us*          __restrict__ x1cb,
    us*          __restrict__ x1tb,
    us*          __restrict__ g_t)
{
    __shared__ us tileX[32][33];
    __shared__ us tileG[32][33];
    const int tx = threadIdx.x, ty = threadIdx.y;   // 32 x 8
    const int d0 = blockIdx.x * 32, r0 = blockIdx.y * 32;
    const int d = d0 + tx;
    const float w0 = cw[d*4+0], w1 = cw[d*4+1], w2 = cw[d*4+2], w3 = cw[d*4+3];
    const float bias = cb[d];
    for (int i = ty; i < 32; i += 8) {
        int row = r0 + i;
        int t = row & (T_ - 1);
        const float* base = x1pre + (size_t)row * D_ + d;
        float acc = bias;
        acc = fmaf(w3, base[0], acc);
        if (t >= 1) acc = fmaf(w2, base[-D_],   acc);
        if (t >= 2) acc = fmaf(w1, base[-2*D_], acc);
        if (t >= 3) acc = fmaf(w0, base[-3*D_], acc);
        float sg = 1.f / (1.f + __expf(-acc));
        us uv = f2us(acc * sg);
        x1cb[(size_t)row * D_ + d] = uv;
        tileX[i][tx] = uv;
        tileG[i][tx] = g_rm[(size_t)row * D_ + d];
    }
    __syncthreads();
    for (int i = ty; i < 32; i += 8) {
        x1tb[(size_t)(d0 + i) * ROWS + r0 + tx] = tileX[tx][i];
        g_t [(size_t)(d0 + i) * ROWS + r0 + tx] = tileG[tx][i];
    }
}

// ------- chunked selective scan + gate, TWO channels per block ---------------
// v6: B/C depend only on (b,t,n) -- pairing channels (d0, d0+1) in the same
// thread shares every Bv/Cv load + address chain between two INDEPENDENT
// recurrence chains (2x ILP for the latency-bound v5). 128 threads =
// (chunk c 0..31) x (state-group ng 0..3); each thread: 4 states x 2 channels.
__global__ __launch_bounds__(128, 4) void scan_block_kernel(
    const float* __restrict__ delta_t,
    const us*    __restrict__ x1tb,
    const float* __restrict__ bct,    // [rows][32]: [0:16]=B_n, [16:32]=C_n
    const float* __restrict__ A_log,
    const us*    __restrict__ g_t,
    us*          __restrict__ y_t)
{
    __shared__ float ysA[T_ + NCH];   // swizzle f(t) = t + (t>>5)
    __shared__ float ysB[T_ + NCH];
    __shared__ f4 PSl[2][NCH][9];     // [ch][c][2ng+(0,1)]; +1 pad col

    const int tid = threadIdx.x;       // 128
    const int pr = blockIdx.x & (D_/2 - 1);
    const int b  = blockIdx.x >> 10;
    const int d0 = pr * 2;
    const int ng = tid & 3;            // states 4ng .. 4ng+3
    const int c  = tid >> 2;           // chunk 0..31
    const size_t rb  = (size_t)b * T_;
    const size_t cb0 = (size_t)d0 * ROWS + rb;   // ch0; ch1 at +ROWS
    const int t0 = c * CLEN;

    f4 al0 = *(const f4*)&A_log[d0 * N_ + ng * 4];
    f4 al1 = *(const f4*)&A_log[(d0 + 1) * N_ + ng * 4];
    const f2 aA01 = (f2){-__expf(al0[0]), -__expf(al0[1])};
    const f2 aA23 = (f2){-__expf(al0[2]), -__expf(al0[3])};
    const f2 aB01 = (f2){-__expf(al1[0]), -__expf(al1[1])};
    const f2 aB23 = (f2){-__expf(al1[2]), -__expf(al1[3])};

    const float* __restrict__ dpA = delta_t + cb0 + t0;
    const float* __restrict__ dpB = dpA + ROWS;
    const us*    __restrict__ xpA = x1tb + cb0 + t0;
    const us*    __restrict__ xpB = xpA + ROWS;
    const float* __restrict__ bp = bct + (size_t)(rb + t0) * 32 + ng * 4;
    const float* __restrict__ cp = bp + 16;

    // ---------------- pass 1: per-chunk (P, S), both channels ----------------
    f2 PA01={1.f,1.f}, PA23={1.f,1.f}, SA01={0.f,0.f}, SA23={0.f,0.f};
    f2 PB01={1.f,1.f}, PB23={1.f,1.f}, SB01={0.f,0.f}, SB23={0.f,0.f};
#pragma unroll
    for (int g = 0; g < 4; ++g) {
        f4 dA0 = *(const f4*)&dpA[g*8], dA1 = *(const f4*)&dpA[g*8 + 4];
        f4 dB0 = *(const f4*)&dpB[g*8], dB1 = *(const f4*)&dpB[g*8 + 4];
        u8v xA = *(const u8v*)&xpA[g*8];
        u8v xB = *(const u8v*)&xpB[g*8];
#pragma unroll
        for (int j = 0; j < 8; ++j) {
            float djA = (j < 4) ? dA0[j] : dA1[j-4];
            float djB = (j < 4) ? dB0[j] : dB1[j-4];
            f4 Bv = *(const f4*)&bp[(size_t)(g*8 + j) * 32];
            float dxA = djA * us2f(xA[j]);
            float dxB = djB * us2f(xB[j]);
            f2 jA = (f2){djA, djA}, jB = (f2){djB, djB};
            f2 eA01 = jA*aA01, eA23 = jA*aA23;
            f2 eB01 = jB*aB01, eB23 = jB*aB23;
            f2 xA01 = (f2){__expf(eA01.x), __expf(eA01.y)};
            f2 xA23 = (f2){__expf(eA23.x), __expf(eA23.y)};
            f2 xB01 = (f2){__expf(eB01.x), __expf(eB01.y)};
            f2 xB23 = (f2){__expf(eB23.x), __expf(eB23.y)};
            PA01 *= xA01; PA23 *= xA23; PB01 *= xB01; PB23 *= xB23;
            SA01 = xA01*SA01 + (f2){dxA*Bv[0], dxA*Bv[1]};
            SA23 = xA23*SA23 + (f2){dxA*Bv[2], dxA*Bv[3]};
            SB01 = xB01*SB01 + (f2){dxB*Bv[0], dxB*Bv[1]};
            SB23 = xB23*SB23 + (f2){dxB*Bv[2], dxB*Bv[3]};
        }
    }
    PSl[0][c][2*ng+0] = (f4){PA01.x,PA01.y,SA01.x,SA01.y};
    PSl[0][c][2*ng+1] = (f4){PA23.x,PA23.y,SA23.x,SA23.y};
    PSl[1][c][2*ng+0] = (f4){PB01.x,PB01.y,SB01.x,SB01.y};
    PSl[1][c][2*ng+1] = (f4){PB23.x,PB23.y,SB23.x,SB23.y};
    __syncthreads();

    // ---------------- inter-chunk prefix (serial over c2 < c) ----------------
    f2 hA01={0.f,0.f}, hA23={0.f,0.f}, hB01={0.f,0.f}, hB23={0.f,0.f};
    for (int c2 = 0; c2 < c; ++c2) {
        f4 p0 = PSl[0][c2][2*ng+0], p1 = PSl[0][c2][2*ng+1];
        f4 q0 = PSl[1][c2][2*ng+0], q1 = PSl[1][c2][2*ng+1];
        hA01 = (f2){p0[0],p0[1]}*hA01 + (f2){p0[2],p0[3]};
        hA23 = (f2){p1[0],p1[1]}*hA23 + (f2){p1[2],p1[3]};
        hB01 = (f2){q0[0],q0[1]}*hB01 + (f2){q0[2],q0[3]};
        hB23 = (f2){q1[0],q1[1]}*hB23 + (f2){q1[2],q1[3]};
    }

    // ---------------- pass 2: recompute a/d, emit y (both channels) ----------
#pragma unroll
    for (int g = 0; g < 4; ++g) {
        f4 dA0 = *(const f4*)&dpA[g*8], dA1 = *(const f4*)&dpA[g*8 + 4];
        f4 dB0 = *(const f4*)&dpB[g*8], dB1 = *(const f4*)&dpB[g*8 + 4];
        u8v xA = *(const u8v*)&xpA[g*8];
        u8v xB = *(const u8v*)&xpB[g*8];
#pragma unroll
        for (int j = 0; j < 8; ++j) {
            float djA = (j < 4) ? dA0[j] : dA1[j-4];
            float djB = (j < 4) ? dB0[j] : dB1[j-4];
            f4 Bv = *(const f4*)&bp[(size_t)(g*8 + j) * 32];
            f4 Cv = *(const f4*)&cp[(size_t)(g*8 + j) * 32];
            float dxA = djA * us2f(xA[j]);
            float dxB = djB * us2f(xB[j]);
            f2 jA = (f2){djA, djA}, jB = (f2){djB, djB};
            f2 eA01 = jA*aA01, eA23 = jA*aA23;
            f2 eB01 = jB*aB01, eB23 = jB*aB23;
            f2 xA01 = (f2){__expf(eA01.x), __expf(eA01.y)};
            f2 xA23 = (f2){__expf(eA23.x), __expf(eA23.y)};
            f2 xB01 = (f2){__expf(eB01.x), __expf(eB01.y)};
            f2 xB23 = (f2){__expf(eB23.x), __expf(eB23.y)};
            hA01 = xA01*hA01 + (f2){dxA*Bv[0], dxA*Bv[1]};
            hA23 = xA23*hA23 + (f2){dxA*Bv[2], dxA*Bv[3]};
            hB01 = xB01*hB01 + (f2){dxB*Bv[0], dxB*Bv[1]};
            hB23 = xB23*hB23 + (f2){dxB*Bv[2], dxB*Bv[3]};
            float sA = (hA01.x*Cv[0] + hA01.y*Cv[1]) + (hA23.x*Cv[2] + hA23.y*Cv[3]);
            float sB = (hB01.x*Cv[0] + hB01.y*Cv[1]) + (hB23.x*Cv[2] + hB23.y*Cv[3]);
            sA = sum4_quad(sA);
            sB = sum4_quad(sB);
            int t = t0 + g*8 + j;
            if (ng == 0) { ysA[t + (t >> 5)] = sA; ysB[t + (t >> 5)] = sB; }
        }
    }
    __syncthreads();

    // ---------------- gated coalesced output, both channels ----------------
    {
        int i = tid * 8;                   // 128 threads x 8 t's per channel
        int fi = i + (i >> 5);
        u8v ugA = *(const u8v*)&g_t[cb0 + i];
        u8v ugB = *(const u8v*)&g_t[cb0 + ROWS + i];
        u8v uyA, uyB;
#pragma unroll
        for (int k = 0; k < 8; ++k) {
            float gA = us2f(ugA[k]), gB = us2f(ugB[k]);
            uyA[k] = f2us(ysA[fi + k] * gA * (1.f / (1.f + __expf(-gA))));
            uyB[k] = f2us(ysB[fi + k] * gB * (1.f / (1.f + __expf(-gB))));
        }
        *(u8v*)&y_t[cb0 + i] = uyA;
        *(u8v*)&y_t[cb0 + ROWS + i] = uyB;
    }
}

extern "C" void kernel_launch(void* const* d_in, const int* in_sizes, int n_in,
                              void* d_out, int out_size, void* d_ws, size_t ws_size,
                              hipStream_t stream)
{
    const float* x      = (const float*)d_in[0];
    const float* rms_w  = (const float*)d_in[1];
    const float* in_W   = (const float*)d_in[2];
    const float* in_b   = (const float*)d_in[3];
    const float* conv_w = (const float*)d_in[4];
    const float* conv_b = (const float*)d_in[5];
    const float* A_log  = (const float*)d_in[6];
    const float* dbc_W  = (const float*)d_in[7];
    const float* dbc_b  = (const float*)d_in[8];
    const float* dup_W  = (const float*)d_in[9];
    const float* dup_b  = (const float*)d_in[10];
    const float* out_W  = (const float*)d_in[11];
    const float* out_b  = (const float*)d_in[12];
    float* out = (float*)d_out;

    // ---- workspace layout (~83 MB; 89.3 MB proven available) ----
    float* ws      = (float*)d_ws;
    float* x1pre   = ws;                           // 16 MB fp32 [rows][D], dead after conv
    us* g_rm  = (us*)(x1pre + (size_t)ROWS*D_);    // 8 MB bf16 [rows][D], dead after conv
    us* g_t   = g_rm  + (size_t)ROWS*D_;           // 8 MB bf16 [d][rows]
    float* bct     = (float*)(g_t + (size_t)ROWS*D_); // 256 KB fp32 [rows][32] (B|C)
    float* delta_t = bct + (size_t)2*N_*ROWS;      // 16 MB fp32 [d][rows]
    us* hbf   = (us*)(delta_t + (size_t)ROWS*D_);  // 4 MB
    us* x1cb  = hbf   + (size_t)ROWS*DM_;          // 8 MB [rows][D], dead after dbc-GEMM
    us* x1tb  = x1cb  + (size_t)ROWS*D_;           // 8 MB [d][rows]
    us* dtrb  = x1tb  + (size_t)ROWS*D_;           // 0.5 MB [rows][DTR]
    us* inWt  = dtrb  + (size_t)ROWS*DTR_;         // 8 MB  [4096][1024]
    us* dbcWt = inWt  + (size_t)2*D_*DM_;          // 0.64 MB [160][2048]
    us* dupWt = dbcWt + (size_t)NDBC*D_;           // 0.5 MB [2048][128]
    us* outWt = dupWt + (size_t)D_*DTR_;           // 4 MB  [1024][2048]
    float* dbcPart = x1pre;                        // alias (x1pre dead): 10.5 MB [8][2048][160]
    us* y_t   = (us*)x1pre;                        // alias (partials dead after reduce)
    us* ybf   = x1cb;                              // alias (x1cb dead), [rows][D]
    float* outPart = x1pre;                        // alias (y_t dead after transpose):
                                                   // 32 MiB [4][2048][1024] = x1pre+g_rm+g_t
    dim3 tb(32, 8);
    // 1. weight prep
    prep_weights<<<6720, tb, 0, stream>>>(in_W, out_W, dbc_W, dup_W,
                                          inWt, outWt, dbcWt, dupWt);
    // 2. fused rmsnorm -> hbf (bf16)
    rmshbf_kernel<<<ROWS, 256, 0, stream>>>(x, rms_w, hbf);
    // 3. fused in_proj: x1pre fp32 + g_rm bf16 (both row-major)  [2048 x 4096], K=1024
    mgemm<4,false><<<dim3(32, 16), 256, 0, stream>>>(
        hbf, inWt, in_b, x1pre, g_rm, nullptr, nullptr, ROWS, 2*D_, DM_, DM_);
    // 4. conv + silu -> x1cb + x1tb ; g_rm -> g_t transpose
    conv_silu_kernel<<<dim3(D_/32, ROWS/32), tb, 0, stream>>>(
        x1pre, g_rm, conv_w, conv_b, x1cb, x1tb, g_t);
    // 5. dbc partials, split-K x8: [2048 x 160], K=2048/8=256 per slice
    mgemm<5,false><<<dim3(2, 16, KSPL), 256, 0, stream>>>(
        x1cb, dbcWt, nullptr, dbcPart, nullptr, nullptr, nullptr,
        ROWS, NDBC, D_/KSPL, D_);
    // 5b. reduce partials + bias -> dtrb bf16 + bct fp32
    dbc_reduce<<<ROWS*NDBC/256, 256, 0, stream>>>(dbcPart, dbc_b, dtrb, bct);
    // 6. delta_t = softplus(dup_W^T @ dtr^T + dup_b)  [2048 x 2048], K=128
    mgemm<1,true><<<dim3(16, 16), 256, 0, stream>>>(
        dupWt, dtrb, dup_b, delta_t, nullptr, nullptr, nullptr, D_, ROWS, DTR_, DTR_);
    // 7. paired-channel selective scan + gate -> y_t [d][rows]
    scan_block_kernel<<<B_*D_/2, 128, 0, stream>>>(delta_t, x1tb, bct, A_log, g_t, y_t);
    // 8. y_t -> ybf [rows][D]
    transpose_us<<<dim3(ROWS/32, D_/32), tb, 0, stream>>>(y_t, ybf, D_, ROWS);
    // 9. out-proj partials, split-K x4: [2048 x 1024], K=2048/4=512 per slice
    //    (v6's counters: non-split out-proj ran 128 blocks on 256 CUs ->
    //     Occupancy 4.8%, MfmaUtil 6%, 48.6 us. Split-K fills the GPU.)
    mgemm<5,false><<<dim3(8, 16, OSPL), 256, 0, stream>>>(
        ybf, outWt, nullptr, outPart, nullptr, nullptr, nullptr,
        ROWS, DM_, D_/OSPL, D_);
    // 9b. out = sum partials + out_b + residual
    out_reduce<<<ROWS*DM_/1024, 256, 0, stream>>>(outPart, out_b, x, out);
}

// Round 8
// 244.157 us; speedup vs baseline: 1.3899x; 1.0292x over previous
//
#include <hip/hip_runtime.h>
#include <math.h>

typedef unsigned short us;
typedef __attribute__((ext_vector_type(8))) short frag8;
typedef __attribute__((ext_vector_type(8))) unsigned short u8v;
typedef __attribute__((ext_vector_type(4))) float f4;
typedef __attribute__((ext_vector_type(2))) float f2;

#define B_   2
#define T_   1024
#define DM_  1024
#define D_   2048
#define N_   16
#define DTR_ 128
#define NDBC 160           // DTR + 2N
#define ROWS (B_*T_)       // 2048
#define EPS_ 1e-6f
#define NCH  32            // scan chunks per channel
#define CLEN (T_/NCH)      // 32 steps per chunk
#define KSPL 8             // split-K factor for dbc GEMM
#define OSPL 4             // split-K factor for out-proj GEMM
#define L2E  1.44269504f   // log2(e)

__device__ __forceinline__ float us2f(us s){
    return __uint_as_float(((unsigned int)s) << 16);
}
__device__ __forceinline__ us f2us(float f){   // RTN-even fp32->bf16
    unsigned int u = __float_as_uint(f);
    return (us)((u + 0x7FFF + ((u >> 16) & 1)) >> 16);
}
// raw v_exp_f32: D = 2^S0 (1 instr; __expf emits v_mul(log2e)+v_exp)
__device__ __forceinline__ float exp2i(float x){
    float r; asm("v_exp_f32 %0, %1" : "=v"(r) : "v"(x)); return r;
}
__device__ __forceinline__ float rcpi(float x){
    return __builtin_amdgcn_rcpf(x);
}

// async global->LDS, 16B per lane. LDS dest is wave-uniform base + lane*16.
__device__ __forceinline__ void async16(const void* g, void* l){
    __builtin_amdgcn_global_load_lds(
        (const __attribute__((address_space(1))) void*)g,
        (__attribute__((address_space(3)))       void*)l, 16, 0, 0);
}

// one DPP accumulate step (dpp_ctrl must be a literal constant)
template<int CTRL>
__device__ __forceinline__ float dpp_add(float x){
    int t = __builtin_amdgcn_update_dpp(0, __float_as_int(x), CTRL, 0xF, 0xF, true);
    return x + __int_as_float(t);
}
// 4-lane (quad) sum via two quad_perm DPP adds; all 4 lanes get the total
__device__ __forceinline__ float sum4_quad(float x){
    x = dpp_add<0xB1>(x);   // quad_perm [1,0,3,2]
    x = dpp_add<0x4E>(x);   // quad_perm [2,3,0,1]
    return x;
}

// ---- combined preprocessing: 4 weight transposes + RMSNorm (merged) ----
// bid < 6720: fp32 [R][C] -> bf16 [C][R] weight prep (as before)
// bid >= 6720: RMSNorm row (bid-6720) -> hbf bf16
__global__ __launch_bounds__(256) void prep_weights(
    const float* __restrict__ in_W,  const float* __restrict__ out_W,
    const float* __restrict__ dbc_W, const float* __restrict__ dup_W,
    us* __restrict__ inWt, us* __restrict__ outWt,
    us* __restrict__ dbcWt, us* __restrict__ dupWt,
    const float* __restrict__ x, const float* __restrict__ rms_w,
    us* __restrict__ hbf)
{
    int bid = blockIdx.x;
    int tx = threadIdx.x, ty = threadIdx.y;   // 32 x 8
    if (bid >= 6720) {   // ---- RMSNorm path ----
        const int row = bid - 6720;
        const int tid = ty * 32 + tx;
        const float* xr = x + (size_t)row * DM_;
        float vals[4], ss = 0.f;
#pragma unroll
        for (int i = 0; i < 4; ++i) { vals[i] = xr[tid + i*256]; ss += vals[i]*vals[i]; }
#pragma unroll
        for (int off = 32; off >= 1; off >>= 1) ss += __shfl_xor(ss, off, 64);
        __shared__ float red[4];
        if ((tid & 63) == 0) red[tid >> 6] = ss;
        __syncthreads();
        float scale = rsqrtf((red[0]+red[1]+red[2]+red[3]) / (float)DM_ + EPS_);
#pragma unroll
        for (int i = 0; i < 4; ++i)
            hbf[(size_t)row * DM_ + tid + i*256] = f2us(vals[i] * scale * rms_w[tid + i*256]);
        return;
    }
    __shared__ us tile[32][33];
    const float* src; us* dst; int C, R, TX, rel;
    if (bid < 4096)      { src = in_W;  dst = inWt;  R = 1024; C = 4096; TX = 128; rel = bid; }
    else if (bid < 6144) { src = out_W; dst = outWt; R = 2048; C = 1024; TX = 32;  rel = bid - 4096; }
    else if (bid < 6464) { src = dbc_W; dst = dbcWt; R = 2048; C = 160;  TX = 5;   rel = bid - 6144; }
    else                 { src = dup_W; dst = dupWt; R = 128;  C = 2048; TX = 64;  rel = bid - 6464; }
    int c0 = (rel % TX) * 32, r0 = (rel / TX) * 32;
    for (int i = ty; i < 32; i += 8)
        tile[i][tx] = f2us(src[(size_t)(r0 + i) * C + c0 + tx]);
    __syncthreads();
    for (int i = ty; i < 32; i += 8)
        dst[(size_t)(c0 + i) * R + r0 + tx] = tile[tx][i];
}

// ------------- bf16 [R][C] -> bf16 [C][R] (dims multiples of 32) -------------
__global__ __launch_bounds__(256) void transpose_us(const us* __restrict__ in,
                                                    us* __restrict__ out, int R, int C)
{
    __shared__ us tile[32][33];
    int c0 = blockIdx.x * 32, r0 = blockIdx.y * 32;
    int tx = threadIdx.x, ty = threadIdx.y;   // 32 x 8
    for (int i = ty; i < 32; i += 8)
        tile[i][tx] = in[(size_t)(r0 + i) * C + c0 + tx];
    __syncthreads();
    for (int i = ty; i < 32; i += 8)
        out[(size_t)(c0 + i) * R + r0 + tx] = tile[tx][i];
}

// ---------- MFMA GEMM: C[M,N] = A[M,K](bf16) * Bt[N,K](bf16)^T + bias --------
// 128x128 tile / 4 waves; wave 64x64 via 4x4 mfma_f32_16x16x32_bf16.
// ld = row stride of A and Bt (elements); K = K-range this block loops over.
// EPI 5 (split-K): blockIdx.z selects K-slice, raw partial (no bias) written
// to Cf + z*M*N. Other EPIs as before.
template<int EPI, bool RB>
__global__ __launch_bounds__(256) void mgemm(
    const us*    __restrict__ A,     // [M][ld]
    const us*    __restrict__ Bt,    // [N][ld]
    const float* __restrict__ bias,
    float*       __restrict__ Cf,
    us*          __restrict__ Caux,
    const float* __restrict__ resid, // EPI==2
    float*       __restrict__ bct,   // EPI==3
    int M, int N, int K, int ld)
{
    __shared__ us As[128*64];
    __shared__ us Bs[128*64];
    const int tid = threadIdx.x;
    const int bm = blockIdx.y * 128;
    const int bn = blockIdx.x * 128;
    const int w = tid >> 6, lane = tid & 63;
    const int wr = w >> 1, wc = w & 1;
    const int m16 = lane & 15, quad = lane >> 4;

    const us* Ak = A;
    const us* Bk = Bt;
    if constexpr (EPI == 5) {
        const size_t koff = (size_t)blockIdx.z * K;
        Ak += koff; Bk += koff;
        Cf += (size_t)blockIdx.z * (size_t)M * N;
    }

    f4 acc[4][4];
#pragma unroll
    for (int i = 0; i < 4; ++i)
#pragma unroll
        for (int j = 0; j < 4; ++j)
            acc[i][j] = (f4){0.f, 0.f, 0.f, 0.f};

    for (int k0 = 0; k0 < K; k0 += 64) {
        __syncthreads();   // prior iter's frag reads done before overwrite
#pragma unroll
        for (int q = 0; q < 4; ++q) {
            int cb = (w*4 + q)*64 + lane;       // 16B-chunk id 0..1023
            int row = cb >> 3, c8 = (cb & 7)*8;
            async16(Ak + (size_t)(bm + row) * ld + k0 + c8, &As[cb*8]);
            async16(Bk + (size_t)(bn + row) * ld + k0 + c8, &Bs[cb*8]);
        }
        __syncthreads();   // vmcnt(0) drained here -> LDS valid
#pragma unroll
        for (int ks = 0; ks < 64; ks += 32) {
            frag8 af[4], bfr[4];
#pragma unroll
            for (int i = 0; i < 4; ++i)
                af[i] = *(const frag8*)&As[(wr*64 + i*16 + m16)*64 + ks + quad*8];
#pragma unroll
            for (int j = 0; j < 4; ++j)
                bfr[j] = *(const frag8*)&Bs[(wc*64 + j*16 + m16)*64 + ks + quad*8];
#pragma unroll
            for (int i = 0; i < 4; ++i)
#pragma unroll
                for (int j = 0; j < 4; ++j)
                    acc[i][j] = __builtin_amdgcn_mfma_f32_16x16x32_bf16(af[i], bfr[j], acc[i][j], 0, 0, 0);
        }
    }

#pragma unroll
    for (int i = 0; i < 4; ++i) {
#pragma unroll
        for (int j = 0; j < 4; ++j) {
            int col = bn + wc*64 + j*16 + m16;
            if (col >= N) continue;
            float bvc = (RB || EPI == 5) ? 0.f : bias[col];
#pragma unroll
            for (int r = 0; r < 4; ++r) {
                int row = bm + wr*64 + i*16 + quad*4 + r;
                float v = acc[i][j][r] + (EPI == 5 ? 0.f : (RB ? bias[row] : bvc));
                if constexpr (EPI == 1) {
                    v = fmaxf(v, 0.f) + __logf(1.f + __expf(-fabsf(v)));
                    Cf[(size_t)row * N + col] = v;
                } else if constexpr (EPI == 2) {
                    v += resid[(size_t)row * N + col];
                    Cf[(size_t)row * N + col] = v;
                } else if constexpr (EPI == 3) {
                    if (col < DTR_) Caux[(size_t)row * DTR_ + col] = f2us(v);
                    else            bct [(size_t)row * 32 + (col - DTR_)] = v;
                } else if constexpr (EPI == 4) {
                    if (col < D_) Cf  [(size_t)row * D_ + col]        = v;
                    else          Caux[(size_t)row * D_ + (col - D_)] = f2us(v);
                } else {   // EPI 0 and EPI 5 (partial)
                    Cf[(size_t)row * N + col] = v;
                }
            }
        }
    }
}

// ---- split-K reduce for dbc: sum 8 partials + bias -> dtrb bf16 + bct fp32 ----
__global__ __launch_bounds__(256) void dbc_reduce(
    const float* __restrict__ part,   // [KSPL][ROWS][NDBC]
    const float* __restrict__ bias,
    us*    __restrict__ dtrb,         // [ROWS][DTR]
    float* __restrict__ bct)          // [ROWS][32]
{
    int idx = blockIdx.x * 256 + threadIdx.x;   // < ROWS*NDBC
    int row = idx / NDBC, col = idx - row * NDBC;
    float v = bias[col];
#pragma unroll
    for (int z = 0; z < KSPL; ++z)
        v += part[(size_t)z * ROWS * NDBC + idx];
    if (col < DTR_) dtrb[(size_t)row * DTR_ + col] = f2us(v);
    else            bct [(size_t)row * 32 + (col - DTR_)] = v;
}

// ---- split-K reduce for out-proj: sum 4 partials + bias + residual ----
__global__ __launch_bounds__(256) void out_reduce(
    const float* __restrict__ part,   // [OSPL][ROWS][DM_]
    const float* __restrict__ bias,   // [DM_]
    const float* __restrict__ resid,  // [ROWS][DM_]
    float* __restrict__ out)
{
    int idx = (blockIdx.x * 256 + threadIdx.x) * 4;  // element index, f4 chunks
    int col = idx & (DM_ - 1);
    f4 v = *(const f4*)&bias[col];
    v += *(const f4*)&resid[idx];
#pragma unroll
    for (int z = 0; z < OSPL; ++z)
        v += *(const f4*)&part[(size_t)z * ROWS * DM_ + idx];
    *(f4*)&out[idx] = v;
}

// --- depthwise causal conv (K=4) + SiLU, dual-layout x1 out + g transpose ---
__global__ __launch_bounds__(256) void conv_silu_kernel(
    const float* __restrict__ x1pre,
    const us*    __restrict__ g_rm,
    const float* __restrict__ cw,
    const float* __restrict__ cb,
    us*          __restrict__ x1cb,
    us*          __restrict__ x1tb,
    us*          __restrict__ g_t)
{
    __shared__ us tileX[32][33];
    __shared__ us tileG[32][33];
    const int tx = threadIdx.x, ty = threadIdx.y;   // 32 x 8
    const int d0 = blockIdx.x * 32, r0 = blockIdx.y * 32;
    const int d = d0 + tx;
    const float w0 = cw[d*4+0], w1 = cw[d*4+1], w2 = cw[d*4+2], w3 = cw[d*4+3];
    const float bias = cb[d];
    for (int i = ty; i < 32; i += 8) {
        int row = r0 + i;
        int t = row & (T_ - 1);
        const float* base = x1pre + (size_t)row * D_ + d;
        float acc = bias;
        acc = fmaf(w3, base[0], acc);
        if (t >= 1) acc = fmaf(w2, base[-D_],   acc);
        if (t >= 2) acc = fmaf(w1, base[-2*D_], acc);
        if (t >= 3) acc = fmaf(w0, base[-3*D_], acc);
        float sg = rcpi(1.f + exp2i(-acc * L2E));
        us uv = f2us(acc * sg);
        x1cb[(size_t)row * D_ + d] = uv;
        tileX[i][tx] = uv;
        tileG[i][tx] = g_rm[(size_t)row * D_ + d];
    }
    __syncthreads();
    for (int i = ty; i < 32; i += 8) {
        x1tb[(size_t)(d0 + i) * ROWS + r0 + tx] = tileX[tx][i];
        g_t [(size_t)(d0 + i) * ROWS + r0 + tx] = tileG[tx][i];
    }
}

// ------- chunked selective scan + gate, TWO channels per block ---------------
// v8: VALU-trim on v6's structure (issue ~= 56% of 42us, so trims pay ~1:2):
//  (a) ac2 = -exp(A_log)*log2e folded per state -> raw v_exp_f32 (exp2i), no
//      hidden v_mul per exp (saves 512 mul/thread);
//  (b) P_n = exp2(ac2_n * sum(delta)) -- one scalar Dsum add/step replaces the
//      4-mul/ch/step P-product (identical math, fewer roundings);
//  (c) sigmoids via exp2i + v_rcp (output is bf16; 1-ulp rcp is plenty).
__global__ __launch_bounds__(128, 4) void scan_block_kernel(
    const float* __restrict__ delta_t,
    const us*    __restrict__ x1tb,
    const float* __restrict__ bct,    // [rows][32]: [0:16]=B_n, [16:32]=C_n
    const float* __restrict__ A_log,
    const us*    __restrict__ g_t,
    us*          __restrict__ y_t)
{
    __shared__ float ysA[T_ + NCH];   // swizzle f(t) = t + (t>>5)
    __shared__ float ysB[T_ + NCH];
    __shared__ f4 PSl[2][NCH][9];     // [ch][c][2ng+(0,1)]; +1 pad col

    const int tid = threadIdx.x;       // 128
    const int pr = blockIdx.x & (D_/2 - 1);
    const int b  = blockIdx.x >> 10;
    const int d0 = pr * 2;
    const int ng = tid & 3;            // states 4ng .. 4ng+3
    const int c  = tid >> 2;           // chunk 0..31
    const size_t rb  = (size_t)b * T_;
    const size_t cb0 = (size_t)d0 * ROWS + rb;   // ch0; ch1 at +ROWS
    const int t0 = c * CLEN;

    // per-state coefficients ac2_n = -exp(A_log[d][n]) * log2(e)
    f4 al0 = *(const f4*)&A_log[d0 * N_ + ng * 4];
    f4 al1 = *(const f4*)&A_log[(d0 + 1) * N_ + ng * 4];
    const f2 aA01 = (f2){-__expf(al0[0])*L2E, -__expf(al0[1])*L2E};
    const f2 aA23 = (f2){-__expf(al0[2])*L2E, -__expf(al0[3])*L2E};
    const f2 aB01 = (f2){-__expf(al1[0])*L2E, -__expf(al1[1])*L2E};
    const f2 aB23 = (f2){-__expf(al1[2])*L2E, -__expf(al1[3])*L2E};

    const float* __restrict__ dpA = delta_t + cb0 + t0;
    const float* __restrict__ dpB = dpA + ROWS;
    const us*    __restrict__ xpA = x1tb + cb0 + t0;
    const us*    __restrict__ xpB = xpA + ROWS;
    const float* __restrict__ bp = bct + (size_t)(rb + t0) * 32 + ng * 4;
    const float* __restrict__ cp = bp + 16;

    // ---------------- pass 1: per-chunk (Dsum, S), both channels -------------
    float DsA = 0.f, DsB = 0.f;
    f2 SA01={0.f,0.f}, SA23={0.f,0.f};
    f2 SB01={0.f,0.f}, SB23={0.f,0.f};
#pragma unroll
    for (int g = 0; g < 4; ++g) {
        f4 dA0 = *(const f4*)&dpA[g*8], dA1 = *(const f4*)&dpA[g*8 + 4];
        f4 dB0 = *(const f4*)&dpB[g*8], dB1 = *(const f4*)&dpB[g*8 + 4];
        u8v xA = *(const u8v*)&xpA[g*8];
        u8v xB = *(const u8v*)&xpB[g*8];
#pragma unroll
        for (int j = 0; j < 8; ++j) {
            float djA = (j < 4) ? dA0[j] : dA1[j-4];
            float djB = (j < 4) ? dB0[j] : dB1[j-4];
            f4 Bv = *(const f4*)&bp[(size_t)(g*8 + j) * 32];
            float dxA = djA * us2f(xA[j]);
            float dxB = djB * us2f(xB[j]);
            DsA += djA; DsB += djB;
            f2 jA = (f2){djA, djA}, jB = (f2){djB, djB};
            f2 eA01 = jA*aA01, eA23 = jA*aA23;
            f2 eB01 = jB*aB01, eB23 = jB*aB23;
            f2 xA01 = (f2){exp2i(eA01.x), exp2i(eA01.y)};
            f2 xA23 = (f2){exp2i(eA23.x), exp2i(eA23.y)};
            f2 xB01 = (f2){exp2i(eB01.x), exp2i(eB01.y)};
            f2 xB23 = (f2){exp2i(eB23.x), exp2i(eB23.y)};
            SA01 = xA01*SA01 + (f2){dxA*Bv[0], dxA*Bv[1]};
            SA23 = xA23*SA23 + (f2){dxA*Bv[2], dxA*Bv[3]};
            SB01 = xB01*SB01 + (f2){dxB*Bv[0], dxB*Bv[1]};
            SB23 = xB23*SB23 + (f2){dxB*Bv[2], dxB*Bv[3]};
        }
    }
    // P_n = exp2(ac2_n * Dsum) -- replaces per-step P products
    f2 PA01 = (f2){exp2i(aA01.x*DsA), exp2i(aA01.y*DsA)};
    f2 PA23 = (f2){exp2i(aA23.x*DsA), exp2i(aA23.y*DsA)};
    f2 PB01 = (f2){exp2i(aB01.x*DsB), exp2i(aB01.y*DsB)};
    f2 PB23 = (f2){exp2i(aB23.x*DsB), exp2i(aB23.y*DsB)};
    PSl[0][c][2*ng+0] = (f4){PA01.x,PA01.y,SA01.x,SA01.y};
    PSl[0][c][2*ng+1] = (f4){PA23.x,PA23.y,SA23.x,SA23.y};
    PSl[1][c][2*ng+0] = (f4){PB01.x,PB01.y,SB01.x,SB01.y};
    PSl[1][c][2*ng+1] = (f4){PB23.x,PB23.y,SB23.x,SB23.y};
    __syncthreads();

    // ---------------- inter-chunk prefix (serial over c2 < c) ----------------
    f2 hA01={0.f,0.f}, hA23={0.f,0.f}, hB01={0.f,0.f}, hB23={0.f,0.f};
    for (int c2 = 0; c2 < c; ++c2) {
        f4 p0 = PSl[0][c2][2*ng+0], p1 = PSl[0][c2][2*ng+1];
        f4 q0 = PSl[1][c2][2*ng+0], q1 = PSl[1][c2][2*ng+1];
        hA01 = (f2){p0[0],p0[1]}*hA01 + (f2){p0[2],p0[3]};
        hA23 = (f2){p1[0],p1[1]}*hA23 + (f2){p1[2],p1[3]};
        hB01 = (f2){q0[0],q0[1]}*hB01 + (f2){q0[2],q0[3]};
        hB23 = (f2){q1[0],q1[1]}*hB23 + (f2){q1[2],q1[3]};
    }

    // ---------------- pass 2: recompute a/d, emit y (both channels) ----------
#pragma unroll
    for (int g = 0; g < 4; ++g) {
        f4 dA0 = *(const f4*)&dpA[g*8], dA1 = *(const f4*)&dpA[g*8 + 4];
        f4 dB0 = *(const f4*)&dpB[g*8], dB1 = *(const f4*)&dpB[g*8 + 4];
        u8v xA = *(const u8v*)&xpA[g*8];
        u8v xB = *(const u8v*)&xpB[g*8];
#pragma unroll
        for (int j = 0; j < 8; ++j) {
            float djA = (j < 4) ? dA0[j] : dA1[j-4];
            float djB = (j < 4) ? dB0[j] : dB1[j-4];
            f4 Bv = *(const f4*)&bp[(size_t)(g*8 + j) * 32];
            f4 Cv = *(const f4*)&cp[(size_t)(g*8 + j) * 32];
            float dxA = djA * us2f(xA[j]);
            float dxB = djB * us2f(xB[j]);
            f2 jA = (f2){djA, djA}, jB = (f2){djB, djB};
            f2 eA01 = jA*aA01, eA23 = jA*aA23;
            f2 eB01 = jB*aB01, eB23 = jB*aB23;
            f2 xA01 = (f2){exp2i(eA01.x), exp2i(eA01.y)};
            f2 xA23 = (f2){exp2i(eA23.x), exp2i(eA23.y)};
            f2 xB01 = (f2){exp2i(eB01.x), exp2i(eB01.y)};
            f2 xB23 = (f2){exp2i(eB23.x), exp2i(eB23.y)};
            hA01 = xA01*hA01 + (f2){dxA*Bv[0], dxA*Bv[1]};
            hA23 = xA23*hA23 + (f2){dxA*Bv[2], dxA*Bv[3]};
            hB01 = xB01*hB01 + (f2){dxB*Bv[0], dxB*Bv[1]};
            hB23 = xB23*hB23 + (f2){dxB*Bv[2], dxB*Bv[3]};
            float sA = (hA01.x*Cv[0] + hA01.y*Cv[1]) + (hA23.x*Cv[2] + hA23.y*Cv[3]);
            float sB = (hB01.x*Cv[0] + hB01.y*Cv[1]) + (hB23.x*Cv[2] + hB23.y*Cv[3]);
            sA = sum4_quad(sA);
            sB = sum4_quad(sB);
            int t = t0 + g*8 + j;
            if (ng == 0) { ysA[t + (t >> 5)] = sA; ysB[t + (t >> 5)] = sB; }
        }
    }
    __syncthreads();

    // ---------------- gated coalesced output, both channels ----------------
    {
        int i = tid * 8;                   // 128 threads x 8 t's per channel
        int fi = i + (i >> 5);
        u8v ugA = *(const u8v*)&g_t[cb0 + i];
        u8v ugB = *(const u8v*)&g_t[cb0 + ROWS + i];
        u8v uyA, uyB;
#pragma unroll
        for (int k = 0; k < 8; ++k) {
            float gA = us2f(ugA[k]), gB = us2f(ugB[k]);
            uyA[k] = f2us(ysA[fi + k] * gA * rcpi(1.f + exp2i(-gA * L2E)));
            uyB[k] = f2us(ysB[fi + k] * gB * rcpi(1.f + exp2i(-gB * L2E)));
        }
        *(u8v*)&y_t[cb0 + i] = uyA;
        *(u8v*)&y_t[cb0 + ROWS + i] = uyB;
    }
}

extern "C" void kernel_launch(void* const* d_in, const int* in_sizes, int n_in,
                              void* d_out, int out_size, void* d_ws, size_t ws_size,
                              hipStream_t stream)
{
    const float* x      = (const float*)d_in[0];
    const float* rms_w  = (const float*)d_in[1];
    const float* in_W   = (const float*)d_in[2];
    const float* in_b   = (const float*)d_in[3];
    const float* conv_w = (const float*)d_in[4];
    const float* conv_b = (const float*)d_in[5];
    const float* A_log  = (const float*)d_in[6];
    const float* dbc_W  = (const float*)d_in[7];
    const float* dbc_b  = (const float*)d_in[8];
    const float* dup_W  = (const float*)d_in[9];
    const float* dup_b  = (const float*)d_in[10];
    const float* out_W  = (const float*)d_in[11];
    const float* out_b  = (const float*)d_in[12];
    float* out = (float*)d_out;

    // ---- workspace layout (~83 MB; 89.3 MB proven available) ----
    float* ws      = (float*)d_ws;
    float* x1pre   = ws;                           // 16 MB fp32 [rows][D], dead after conv
    us* g_rm  = (us*)(x1pre + (size_t)ROWS*D_);    // 8 MB bf16 [rows][D], dead after conv
    us* g_t   = g_rm  + (size_t)ROWS*D_;           // 8 MB bf16 [d][rows]
    float* bct     = (float*)(g_t + (size_t)ROWS*D_); // 256 KB fp32 [rows][32] (B|C)
    float* delta_t = bct + (size_t)2*N_*ROWS;      // 16 MB fp32 [d][rows]
    us* hbf   = (us*)(delta_t + (size_t)ROWS*D_);  // 4 MB
    us* x1cb  = hbf   + (size_t)ROWS*DM_;          // 8 MB [rows][D], dead after dbc-GEMM
    us* x1tb  = x1cb  + (size_t)ROWS*D_;           // 8 MB [d][rows]
    us* dtrb  = x1tb  + (size_t)ROWS*D_;           // 0.5 MB [rows][DTR]
    us* inWt  = dtrb  + (size_t)ROWS*DTR_;         // 8 MB  [4096][1024]
    us* dbcWt = inWt  + (size_t)2*D_*DM_;          // 0.64 MB [160][2048]
    us* dupWt = dbcWt + (size_t)NDBC*D_;           // 0.5 MB [2048][128]
    us* outWt = dupWt + (size_t)D_*DTR_;           // 4 MB  [1024][2048]
    float* dbcPart = x1pre;                        // alias (x1pre dead): 10.5 MB [8][2048][160]
    us* y_t   = (us*)x1pre;                        // alias (partials dead after reduce)
    us* ybf   = x1cb;                              // alias (x1cb dead), [rows][D]
    float* outPart = x1pre;                        // alias (y_t dead after transpose):
                                                   // 32 MiB [4][2048][1024] = x1pre+g_rm+g_t
    dim3 tb(32, 8);
    // 1. weight prep + fused rmsnorm (6720 prep blocks + 2048 rms blocks)
    prep_weights<<<6720 + ROWS, tb, 0, stream>>>(in_W, out_W, dbc_W, dup_W,
                                                 inWt, outWt, dbcWt, dupWt,
                                                 x, rms_w, hbf);
    // 3. fused in_proj: x1pre fp32 + g_rm bf16 (both row-major)  [2048 x 4096], K=1024
    mgemm<4,false><<<dim3(32, 16), 256, 0, stream>>>(
        hbf, inWt, in_b, x1pre, g_rm, nullptr, nullptr, ROWS, 2*D_, DM_, DM_);
    // 4. conv + silu -> x1cb + x1tb ; g_rm -> g_t transpose
    conv_silu_kernel<<<dim3(D_/32, ROWS/32), tb, 0, stream>>>(
        x1pre, g_rm, conv_w, conv_b, x1cb, x1tb, g_t);
    // 5. dbc partials, split-K x8: [2048 x 160], K=2048/8=256 per slice
    mgemm<5,false><<<dim3(2, 16, KSPL), 256, 0, stream>>>(
        x1cb, dbcWt, nullptr, dbcPart, nullptr, nullptr, nullptr,
        ROWS, NDBC, D_/KSPL, D_);
    // 5b. reduce partials + bias -> dtrb bf16 + bct fp32
    dbc_reduce<<<ROWS*NDBC/256, 256, 0, stream>>>(dbcPart, dbc_b, dtrb, bct);
    // 6. delta_t = softplus(dup_W^T @ dtr^T + dup_b)  [2048 x 2048], K=128
    mgemm<1,true><<<dim3(16, 16), 256, 0, stream>>>(
        dupWt, dtrb, dup_b, delta_t, nullptr, nullptr, nullptr, D_, ROWS, DTR_, DTR_);
    // 7. paired-channel selective scan + gate -> y_t [d][rows]
    scan_block_kernel<<<B_*D_/2, 128, 0, stream>>>(delta_t, x1tb, bct, A_log, g_t, y_t);
    // 8. y_t -> ybf [rows][D]
    transpose_us<<<dim3(ROWS/32, D_/32), tb, 0, stream>>>(y_t, ybf, D_, ROWS);
    // 9. out-proj partials, split-K x4: [2048 x 1024], K=2048/4=512 per slice
    mgemm<5,false><<<dim3(8, 16, OSPL), 256, 0, stream>>>(
        ybf, outWt, nullptr, outPart, nullptr, nullptr, nullptr,
        ROWS, DM_, D_/OSPL, D_);
    // 9b. out = sum partials + out_b + residual
    out_reduce<<<ROWS*DM_/1024, 256, 0, stream>>>(outPart, out_b, x, out);
}